// Round 5
// baseline (503.574 us; speedup 1.0000x reference)
//
#include <hip/hip_runtime.h>
#include <math.h>

typedef __bf16 bf16;
typedef __bf16 bf16x4 __attribute__((ext_vector_type(4)));
typedef __bf16 bf16x8 __attribute__((ext_vector_type(8)));
typedef float floatx4 __attribute__((ext_vector_type(4)));

#define BB 2
#define NN 2048
#define DD 512
#define HH 8
#define HD 64
#define RR 64
#define D3 1536
#define NEG_BIG (-1e30f)

// ------------------------------------------------------- f32 -> bf16 convert
// grid = n/1024, block = 256, 4 elems/thread.
__global__ __launch_bounds__(256) void cvt_kernel(
    const float* __restrict__ in, bf16* __restrict__ out) {
    const int i = (blockIdx.x * 256 + threadIdx.x) * 4;
    floatx4 v = *(const floatx4*)(in + i);
    bf16x4 o;
    o[0] = (bf16)v[0]; o[1] = (bf16)v[1]; o[2] = (bf16)v[2]; o[3] = (bf16)v[3];
    *(bf16x4*)(out + i) = o;
}

// ---------------------------------------------------------------- block reduce
__device__ inline float block_reduce_sum256(float v, float* sbuf) {
    const int tid = threadIdx.x;
    #pragma unroll
    for (int o = 32; o > 0; o >>= 1) v += __shfl_xor(v, o, 64);
    __syncthreads();                     // protect sbuf reuse across calls
    if ((tid & 63) == 0) sbuf[tid >> 6] = v;
    __syncthreads();
    return sbuf[0] + sbuf[1] + sbuf[2] + sbuf[3];
}

// ---------------------------------------------------------------- LayerNorm
// in: f32. out: bf16. WANT_INV also emits 1/max(||out_f32||, 1e-12).
template <bool WANT_INV>
__global__ __launch_bounds__(256) void ln_kernel(
    const float* __restrict__ in, const float* __restrict__ gw,
    const float* __restrict__ bw, bf16* __restrict__ out,
    float* __restrict__ invnorm) {
    __shared__ float sbuf[4];
    const int row = blockIdx.x, tid = threadIdx.x;
    const int i0 = tid * 2;
    const float* ip = in + (size_t)row * DD;
    float v0 = ip[i0], v1 = ip[i0 + 1];
    float mean = block_reduce_sum256(v0 + v1, sbuf) * (1.f / DD);
    float d0 = v0 - mean, d1 = v1 - mean;
    float var = block_reduce_sum256(d0 * d0 + d1 * d1, sbuf) * (1.f / DD);
    float rs = rsqrtf(var + 1e-5f);
    float x0 = d0 * rs * gw[i0] + bw[i0];
    float x1 = d1 * rs * gw[i0 + 1] + bw[i0 + 1];
    out[(size_t)row * DD + i0] = (bf16)x0;
    out[(size_t)row * DD + i0 + 1] = (bf16)x1;
    if (WANT_INV) {
        float s2 = block_reduce_sum256(x0 * x0 + x1 * x1, sbuf);
        if (tid == 0) invnorm[row] = 1.f / fmaxf(sqrtf(s2), 1e-12f);
    }
}

// ---------------------------------------------------------------- GEMM (MFMA)
// C[M,N] = A[M,K](bf16) @ B[K,N](bf16) + bias(f32), epilogue by MODE:
//  0: store bf16
//  1: += resid(f32), store f32        (proj + first residual -> mid)
//  2: exact gelu, store bf16          (mlp1)
//  3: += resid(f32), store f32        (mlp2 + second residual -> OUT, f32!)
#define BM 64
#define BN 64
#define BK 32
template <int MODE>
__global__ __launch_bounds__(256) void gemm_kernel(
    const bf16* __restrict__ A, const bf16* __restrict__ B,
    const float* __restrict__ bias, const float* __restrict__ resid,
    void* __restrict__ out, int M, int N, int K) {
    __shared__ __align__(16) bf16 As[BM * BK];
    __shared__ __align__(16) bf16 Bs[BN * BK];   // transposed: [n][k]
    const int tid = threadIdx.x;
    const int rowBase = blockIdx.y * BM;
    const int colBase = blockIdx.x * BN;
    const int w = tid >> 6, lane = tid & 63;
    const int wm = (w >> 1) * 32, wn = (w & 1) * 32;
    const int lr = lane & 15, lq = lane >> 4;

    floatx4 acc[2][2];
    #pragma unroll
    for (int i = 0; i < 2; i++)
        #pragma unroll
        for (int j = 0; j < 2; j++) acc[i][j] = (floatx4){0.f, 0.f, 0.f, 0.f};

    const int arow = tid >> 2, acol = (tid & 3) * 8;   // A: 64 rows x 32 k
    const int brow = tid >> 3, bcol = (tid & 7) * 8;   // B: 32 k x 64 n

    for (int k0 = 0; k0 < K; k0 += BK) {
        bf16x8 av = *(const bf16x8*)(A + (size_t)(rowBase + arow) * K + k0 + acol);
        bf16x8 bv = *(const bf16x8*)(B + (size_t)(k0 + brow) * N + colBase + bcol);
        __syncthreads();
        *(bf16x8*)(As + arow * BK + acol) = av;
        #pragma unroll
        for (int e = 0; e < 8; e++) Bs[(bcol + e) * BK + brow] = bv[e];
        __syncthreads();
        bf16x8 a0 = *(const bf16x8*)(As + (wm + lr) * BK + lq * 8);
        bf16x8 a1 = *(const bf16x8*)(As + (wm + 16 + lr) * BK + lq * 8);
        bf16x8 b0 = *(const bf16x8*)(Bs + (wn + lr) * BK + lq * 8);
        bf16x8 b1 = *(const bf16x8*)(Bs + (wn + 16 + lr) * BK + lq * 8);
        acc[0][0] = __builtin_amdgcn_mfma_f32_16x16x32_bf16(a0, b0, acc[0][0], 0, 0, 0);
        acc[0][1] = __builtin_amdgcn_mfma_f32_16x16x32_bf16(a0, b1, acc[0][1], 0, 0, 0);
        acc[1][0] = __builtin_amdgcn_mfma_f32_16x16x32_bf16(a1, b0, acc[1][0], 0, 0, 0);
        acc[1][1] = __builtin_amdgcn_mfma_f32_16x16x32_bf16(a1, b1, acc[1][1], 0, 0, 0);
    }

    #pragma unroll
    for (int i = 0; i < 2; i++) {
        #pragma unroll
        for (int j = 0; j < 2; j++) {
            #pragma unroll
            for (int r = 0; r < 4; r++) {
                int row = rowBase + wm + i * 16 + lq * 4 + r;
                int col = colBase + wn + j * 16 + lr;
                size_t idx = (size_t)row * N + col;
                float v = acc[i][j][r] + bias[col];
                if (MODE == 0) {
                    ((bf16*)out)[idx] = (bf16)v;
                } else if (MODE == 1) {
                    ((float*)out)[idx] = v + resid[idx];
                } else if (MODE == 2) {
                    float g = 0.5f * v * (1.f + erff(v * 0.70710678118654752f));
                    ((bf16*)out)[idx] = (bf16)g;
                } else {
                    ((float*)out)[idx] = v + resid[idx];
                }
            }
        }
    }
}

// ---------------------------------------------------------------- attention
// one block per (b, n); band m in [n-64, n+64]; j = m - (n-64) in [0,128]
__global__ __launch_bounds__(256) void attn_kernel(
    const bf16* __restrict__ x, const float* __restrict__ invnorm,
    const bf16* __restrict__ qkv, const float* __restrict__ rep_scale,
    const float* __restrict__ rel_bias, bf16* __restrict__ upd) {
    const int row = blockIdx.x;           // b*N + n
    const int b = row >> 11, n = row & (NN - 1);
    const int tid = threadIdx.x;

    __shared__ float xs[DD];
    __shared__ float qs[DD];
    __shared__ float corr_s[132];
    __shared__ float lg[HH][132];
    __shared__ float red[HH][32];
    __shared__ float maxv[HH], sumv[HH], srep[HH];

    const size_t xrow = (size_t)row * DD;
    xs[tid] = (float)x[xrow + tid];
    xs[tid + 256] = (float)x[xrow + tid + 256];
    const size_t qrow = (size_t)row * D3;
    qs[tid] = (float)qkv[qrow + tid];
    qs[tid + 256] = (float)qkv[qrow + tid + 256];
    if (tid < HH) srep[tid] = rep_scale[tid];
    const float invn = invnorm[row];
    __syncthreads();

    // ---- corr: dot(x_n, x_m) * invn_n * invn_m
    {
        const int jj = tid >> 2, dp = tid & 3;   // 64 j-slots x 4 dim-quarters
        for (int jb = 0; jb < 192; jb += 64) {
            int j = jb + jj;
            int m = n - RR + j;
            bool act = (j < 129) && (m >= 0) && (m < NN);
            float acc = 0.f;
            if (act) {
                const bf16* xm = x + ((size_t)(b * NN + m)) * DD + dp * 128;
                const float* xn = xs + dp * 128;
                #pragma unroll 4
                for (int i = 0; i < 128; i += 8) {
                    bf16x8 vv = *(const bf16x8*)(xm + i);
                    #pragma unroll
                    for (int e = 0; e < 8; e++) acc += (float)vv[e] * xn[i + e];
                }
            }
            acc += __shfl_xor(acc, 1, 64);
            acc += __shfl_xor(acc, 2, 64);
            if (act && dp == 0) corr_s[j] = acc * invn * invnorm[b * NN + m];
        }
    }
    __syncthreads();

    // ---- logits = qk*scale + corr*rep_scale[h] + rel_bias, mask -> NEG_BIG
    {
        const int h = tid & 7, jj0 = tid >> 3;   // 32 j-slots x 8 heads
        for (int jb = 0; jb < 160; jb += 32) {
            int j = jb + jj0;
            if (j >= 129) continue;
            int m = n - RR + j;
            float lv;
            if (m >= 0 && m < NN) {
                const bf16* kp = qkv + ((size_t)(b * NN + m)) * D3 + DD + h * HD;
                const float* qp = qs + h * HD;
                float acc = 0.f;
                #pragma unroll
                for (int i = 0; i < HD; i += 8) {
                    bf16x8 kv = *(const bf16x8*)(kp + i);
                    #pragma unroll
                    for (int e = 0; e < 8; e++) acc += (float)kv[e] * qp[i + e];
                }
                lv = acc * 0.125f + corr_s[j] * srep[h] +
                     rel_bias[(size_t)(n - m + NN - 1) * HH + h];
            } else {
                lv = NEG_BIG;
            }
            lg[h][j] = lv;
        }
    }
    __syncthreads();

    // ---- softmax over j (per head), p stored back into lg
    {
        const int h = tid >> 5, lane = tid & 31;
        float mx = NEG_BIG;
        for (int j = lane; j < 129; j += 32) mx = fmaxf(mx, lg[h][j]);
        red[h][lane] = mx;
        __syncthreads();
        if (lane == 0) {
            float m2 = NEG_BIG;
            for (int i = 0; i < 32; i++) m2 = fmaxf(m2, red[h][i]);
            maxv[h] = m2;
        }
        __syncthreads();
        float s = 0.f;
        for (int j = lane; j < 129; j += 32) {
            float e = expf(lg[h][j] - maxv[h]);
            lg[h][j] = e;
            s += e;
        }
        red[h][lane] = s;
        __syncthreads();
        if (lane == 0) {
            float s2 = 0.f;
            for (int i = 0; i < 32; i++) s2 += red[h][i];
            sumv[h] = s2;
        }
        __syncthreads();
    }

    // ---- PV: upd[n, h*64+d] = sum_j p * v[m] / sum
    {
        const int d = tid & 63, h0 = tid >> 6;
        const int jlo = max(0, RR - n), jhi = min(128, NN - 1 - n + RR);
        #pragma unroll
        for (int hh = 0; hh < 2; hh++) {
            int h = h0 + hh * 4;
            float acc = 0.f;
            for (int j = jlo; j <= jhi; j++) {
                int m = n - RR + j;
                acc += lg[h][j] *
                       (float)qkv[((size_t)(b * NN + m)) * D3 + 2 * DD + h * HD + d];
            }
            upd[xrow + h * HD + d] = (bf16)(acc / sumv[h]);
        }
    }
}

// ---------------------------------------------------------------- launch
// Inputs FLOAT32; OUTPUT FLOAT32 (reference computes in f32 throughout).
// Workspace (~30 MiB): invn | wq | wp | w1 | w2 | x(=y) | qkvb(=hgl) | mid.
// upd (bf16, 4 MiB) lives in d_out's first 4 MiB; it is fully consumed by
// gemm<1> before gemm<3> overwrites the whole 8 MiB d_out with f32.
extern "C" void kernel_launch(void* const* d_in, const int* in_sizes, int n_in,
                              void* d_out, int out_size, void* d_ws,
                              size_t ws_size, hipStream_t stream) {
    const float* nodes  = (const float*)d_in[0];
    const float* ln1_g  = (const float*)d_in[1];
    const float* ln1_b  = (const float*)d_in[2];
    const float* qkv_w  = (const float*)d_in[3];
    const float* qkv_b  = (const float*)d_in[4];
    const float* proj_w = (const float*)d_in[5];
    const float* proj_b = (const float*)d_in[6];
    const float* rep_s  = (const float*)d_in[7];
    const float* rel_b  = (const float*)d_in[8];
    const float* ln2_g  = (const float*)d_in[9];
    const float* ln2_b  = (const float*)d_in[10];
    const float* mlp_w1 = (const float*)d_in[11];
    const float* mlp_b1 = (const float*)d_in[12];
    const float* mlp_w2 = (const float*)d_in[13];
    const float* mlp_b2 = (const float*)d_in[14];

    char* p = (char*)d_ws;
    float* invn = (float*)p;            p += (size_t)1 << 20;
    bf16*  wq   = (bf16*)p;             p += (size_t)DD * D3 * 2;
    bf16*  wp   = (bf16*)p;             p += (size_t)DD * DD * 2;
    bf16*  w1   = (bf16*)p;             p += (size_t)DD * 2 * DD * 2;
    bf16*  w2   = (bf16*)p;             p += (size_t)2 * DD * DD * 2;
    bf16*  x    = (bf16*)p;             p += (size_t)BB * NN * DD * 2;
    bf16*  qkvb = (bf16*)p;             p += (size_t)BB * NN * D3 * 2;
    float* mid  = (float*)p;            p += (size_t)BB * NN * DD * 4;
    bf16*  y    = x;                // alias: x dead after attn_kernel
    bf16*  hgl  = qkvb;             // alias: qkvb dead after attn_kernel
    bf16*  upd  = (bf16*)d_out;     // scratch; consumed by gemm<1>, then
                                    // d_out fully rewritten (f32) by gemm<3>

    const int M = BB * NN;  // 4096

    cvt_kernel<<<DD * D3 / 1024, 256, 0, stream>>>(qkv_w, wq);
    cvt_kernel<<<DD * DD / 1024, 256, 0, stream>>>(proj_w, wp);
    cvt_kernel<<<DD * 2 * DD / 1024, 256, 0, stream>>>(mlp_w1, w1);
    cvt_kernel<<<2 * DD * DD / 1024, 256, 0, stream>>>(mlp_w2, w2);

    ln_kernel<true><<<M, 256, 0, stream>>>(nodes, ln1_g, ln1_b, x, invn);
    gemm_kernel<0><<<dim3(D3 / BN, M / BM), 256, 0, stream>>>(
        x, wq, qkv_b, nullptr, qkvb, M, D3, DD);
    attn_kernel<<<M, 256, 0, stream>>>(x, invn, qkvb, rep_s, rel_b, upd);
    gemm_kernel<1><<<dim3(DD / BN, M / BM), 256, 0, stream>>>(
        upd, wp, proj_b, nodes, mid, M, DD, DD);
    ln_kernel<false><<<M, 256, 0, stream>>>(mid, ln2_g, ln2_b, y, nullptr);
    gemm_kernel<2><<<dim3(2 * DD / BN, M / BM), 256, 0, stream>>>(
        y, w1, mlp_b1, nullptr, hgl, M, 2 * DD, DD);
    gemm_kernel<3><<<dim3(DD / BN, M / BM), 256, 0, stream>>>(
        hgl, w2, mlp_b2, mid, (float*)d_out, M, DD, 2 * DD);
}

// Round 7
// 234.569 us; speedup vs baseline: 2.1468x; 2.1468x over previous
//
#include <hip/hip_runtime.h>
#include <math.h>

typedef __bf16 bf16;
typedef __bf16 bf16x4 __attribute__((ext_vector_type(4)));
typedef __bf16 bf16x8 __attribute__((ext_vector_type(8)));
typedef float floatx4 __attribute__((ext_vector_type(4)));

#define BB 2
#define NN 2048
#define DD 512
#define HH 8
#define HD 64
#define RR 64
#define D3 1536
#define NEG_BIG (-1e30f)
#define TQ 32
#define TBAND 160
#define VW 200   // Vt row width: must be > max jsw = 191 (3-bit XOR swizzle)

// ------------------------------------------------------- f32 -> bf16 convert
__global__ __launch_bounds__(256) void cvt_kernel(
    const float* __restrict__ in, bf16* __restrict__ out) {
    const int i = (blockIdx.x * 256 + threadIdx.x) * 4;
    floatx4 v = *(const floatx4*)(in + i);
    bf16x4 o;
    o[0] = (bf16)v[0]; o[1] = (bf16)v[1]; o[2] = (bf16)v[2]; o[3] = (bf16)v[3];
    *(bf16x4*)(out + i) = o;
}

// ---------------------------------------------------------------- block reduce
__device__ inline float block_reduce_sum256(float v, float* sbuf) {
    const int tid = threadIdx.x;
    #pragma unroll
    for (int o = 32; o > 0; o >>= 1) v += __shfl_xor(v, o, 64);
    __syncthreads();
    if ((tid & 63) == 0) sbuf[tid >> 6] = v;
    __syncthreads();
    return sbuf[0] + sbuf[1] + sbuf[2] + sbuf[3];
}

// ---------------------------------------------------------------- LayerNorm
template <bool WANT_INV>
__global__ __launch_bounds__(256) void ln_kernel(
    const float* __restrict__ in, const float* __restrict__ gw,
    const float* __restrict__ bw, bf16* __restrict__ out,
    float* __restrict__ invnorm) {
    __shared__ float sbuf[4];
    const int row = blockIdx.x, tid = threadIdx.x;
    const int i0 = tid * 2;
    const float* ip = in + (size_t)row * DD;
    float v0 = ip[i0], v1 = ip[i0 + 1];
    float mean = block_reduce_sum256(v0 + v1, sbuf) * (1.f / DD);
    float d0 = v0 - mean, d1 = v1 - mean;
    float var = block_reduce_sum256(d0 * d0 + d1 * d1, sbuf) * (1.f / DD);
    float rs = rsqrtf(var + 1e-5f);
    float x0 = d0 * rs * gw[i0] + bw[i0];
    float x1 = d1 * rs * gw[i0 + 1] + bw[i0 + 1];
    out[(size_t)row * DD + i0] = (bf16)x0;
    out[(size_t)row * DD + i0 + 1] = (bf16)x1;
    if (WANT_INV) {
        float s2 = block_reduce_sum256(x0 * x0 + x1 * x1, sbuf);
        if (tid == 0) invnorm[row] = 1.f / fmaxf(sqrtf(s2), 1e-12f);
    }
}

// ---------------------------------------------------------------- GEMM (MFMA)
//  0: store bf16 | 1: +resid f32->f32 | 2: gelu->bf16 | 3: +resid f32->f32 out
#define BM 64
#define BN 64
#define BK 32
template <int MODE>
__global__ __launch_bounds__(256) void gemm_kernel(
    const bf16* __restrict__ A, const bf16* __restrict__ B,
    const float* __restrict__ bias, const float* __restrict__ resid,
    void* __restrict__ out, int M, int N, int K) {
    __shared__ __align__(16) bf16 As[BM * BK];
    __shared__ __align__(16) bf16 Bs[BN * BK];   // transposed: [n][k]
    const int tid = threadIdx.x;
    const int rowBase = blockIdx.y * BM;
    const int colBase = blockIdx.x * BN;
    const int w = tid >> 6, lane = tid & 63;
    const int wm = (w >> 1) * 32, wn = (w & 1) * 32;
    const int lr = lane & 15, lq = lane >> 4;

    floatx4 acc[2][2];
    #pragma unroll
    for (int i = 0; i < 2; i++)
        #pragma unroll
        for (int j = 0; j < 2; j++) acc[i][j] = (floatx4){0.f, 0.f, 0.f, 0.f};

    const int arow = tid >> 2, acol = (tid & 3) * 8;
    const int brow = tid >> 3, bcol = (tid & 7) * 8;

    for (int k0 = 0; k0 < K; k0 += BK) {
        bf16x8 av = *(const bf16x8*)(A + (size_t)(rowBase + arow) * K + k0 + acol);
        bf16x8 bv = *(const bf16x8*)(B + (size_t)(k0 + brow) * N + colBase + bcol);
        __syncthreads();
        *(bf16x8*)(As + arow * BK + acol) = av;
        #pragma unroll
        for (int e = 0; e < 8; e++) Bs[(bcol + e) * BK + brow] = bv[e];
        __syncthreads();
        bf16x8 a0 = *(const bf16x8*)(As + (wm + lr) * BK + lq * 8);
        bf16x8 a1 = *(const bf16x8*)(As + (wm + 16 + lr) * BK + lq * 8);
        bf16x8 b0 = *(const bf16x8*)(Bs + (wn + lr) * BK + lq * 8);
        bf16x8 b1 = *(const bf16x8*)(Bs + (wn + 16 + lr) * BK + lq * 8);
        acc[0][0] = __builtin_amdgcn_mfma_f32_16x16x32_bf16(a0, b0, acc[0][0], 0, 0, 0);
        acc[0][1] = __builtin_amdgcn_mfma_f32_16x16x32_bf16(a0, b1, acc[0][1], 0, 0, 0);
        acc[1][0] = __builtin_amdgcn_mfma_f32_16x16x32_bf16(a1, b0, acc[1][0], 0, 0, 0);
        acc[1][1] = __builtin_amdgcn_mfma_f32_16x16x32_bf16(a1, b1, acc[1][1], 0, 0, 0);
    }

    #pragma unroll
    for (int i = 0; i < 2; i++) {
        #pragma unroll
        for (int j = 0; j < 2; j++) {
            #pragma unroll
            for (int r = 0; r < 4; r++) {
                int row = rowBase + wm + i * 16 + lq * 4 + r;
                int col = colBase + wn + j * 16 + lr;
                size_t idx = (size_t)row * N + col;
                float v = acc[i][j][r] + bias[col];
                if (MODE == 0) {
                    ((bf16*)out)[idx] = (bf16)v;
                } else if (MODE == 1) {
                    ((float*)out)[idx] = v + resid[idx];
                } else if (MODE == 2) {
                    float g = 0.5f * v * (1.f + erff(v * 0.70710678118654752f));
                    ((bf16*)out)[idx] = (bf16)g;
                } else {
                    ((float*)out)[idx] = v + resid[idx];
                }
            }
        }
    }
}

// ---------------------------------------------------------------- attention
// Tiled MFMA version. Block: TQ=32 queries, band of 160 keys, 4 of 8 heads.
// grid = (N/TQ) * 2(head-split) * B = 256 blocks, 256 threads.
__global__ __launch_bounds__(256) void attn_kernel(
    const bf16* __restrict__ x, const float* __restrict__ invnorm,
    const bf16* __restrict__ qkv, const float* __restrict__ rep_scale,
    const float* __restrict__ rel_bias, bf16* __restrict__ upd) {
    __shared__ __align__(16) bf16 Qs[TQ][72];        // +8 pad: bank spread
    __shared__ __align__(16) bf16 Ks[TBAND][72];     // also pass1 x-chunk buf
    __shared__ __align__(16) bf16 Vt[64 * VW];       // transposed V, XOR-swizzled
    __shared__ __align__(16) bf16 Ps[TQ][168];
    __shared__ float relb[4][192];
    __shared__ float invb[TBAND];
    __shared__ float rmax2[TQ][2];
    __shared__ float rsum2[TQ][2];

    const int tid = threadIdx.x;
    const int bid = blockIdx.x;
    const int b = bid & 1;
    const int h0 = ((bid >> 1) & 1) * 4;
    const int n0 = (bid >> 2) * TQ;
    const int bN = b * NN;

    const int w = tid >> 6, lane = tid & 63;
    const int lr = lane & 15, lq = lane >> 4;
    const int rowHalf = (w >> 1) * 16;   // score rows strip (16)
    const int colBase = (w & 1) * 80;    // score cols strip (5 tiles x 16)
    const int c2 = (w & 1) * 32;         // PV col strip (2 tiles x 16)

    // stage invnorm band + rel_bias slice (191 diagonals x 4 heads)
    if (tid < TBAND) {
        int mc = min(max(n0 - RR + tid, 0), NN - 1);
        invb[tid] = invnorm[bN + mc];
    }
    for (int idx = tid; idx < 4 * 191; idx += 256) {
        int hh = idx / 191, dh = idx - hh * 191;
        relb[hh][dh] = rel_bias[(size_t)(dh + (NN - 1 - 95)) * HH + h0 + hh];
    }

    // ---- pass 1: corr accumulation over 8 chunks of 64 dims
    floatx4 cacc[5];
    #pragma unroll
    for (int t = 0; t < 5; t++) cacc[t] = (floatx4){0.f, 0.f, 0.f, 0.f};

    for (int c = 0; c < 8; c++) {
        __syncthreads();
        #pragma unroll
        for (int i = 0; i < 5; i++) {
            int s = i * 256 + tid;
            int j = s >> 3, seg = s & 7;
            int mc = min(max(n0 - RR + j, 0), NN - 1);
            *(bf16x8*)&Ks[j][seg * 8] =
                *(const bf16x8*)(x + (size_t)(bN + mc) * DD + c * 64 + seg * 8);
        }
        __syncthreads();
        #pragma unroll
        for (int kb = 0; kb < 2; kb++) {
            bf16x8 a = *(bf16x8*)&Ks[64 + rowHalf + lr][kb * 32 + lq * 8];
            #pragma unroll
            for (int t = 0; t < 5; t++) {
                bf16x8 bb = *(bf16x8*)&Ks[colBase + t * 16 + lr][kb * 32 + lq * 8];
                cacc[t] = __builtin_amdgcn_mfma_f32_16x16x32_bf16(a, bb, cacc[t], 0, 0, 0);
            }
        }
    }
    __syncthreads();

    // corrv = raw_dot * invn_q * invn_k   (C layout: row=lq*4+r, col=lr)
    float corrv[5][4];
    {
        float invq[4];
        #pragma unroll
        for (int r = 0; r < 4; r++) invq[r] = invb[64 + rowHalf + lq * 4 + r];
        #pragma unroll
        for (int t = 0; t < 5; t++) {
            float invk = invb[colBase + t * 16 + lr];
            #pragma unroll
            for (int r = 0; r < 4; r++) corrv[t][r] = cacc[t][r] * invq[r] * invk;
        }
    }

    // ---- pass 2: per head
    for (int h = h0; h < h0 + 4; h++) {
        {   // Q tile: 32 x 64
            int row = tid >> 3, seg = tid & 7;
            *(bf16x8*)&Qs[row][seg * 8] =
                *(const bf16x8*)(qkv + (size_t)(bN + n0 + row) * D3 + h * HD + seg * 8);
        }
        #pragma unroll
        for (int i = 0; i < 5; i++) {   // K natural + V transposed/swizzled
            int s = i * 256 + tid;
            int j = s >> 3, seg = s & 7;
            int mc = min(max(n0 - RR + j, 0), NN - 1);
            *(bf16x8*)&Ks[j][seg * 8] =
                *(const bf16x8*)(qkv + (size_t)(bN + mc) * D3 + DD + h * HD + seg * 8);
            bf16x8 v = *(const bf16x8*)(qkv + (size_t)(bN + mc) * D3 + 2 * DD + h * HD + seg * 8);
            #pragma unroll
            for (int e = 0; e < 8; e++) {
                int d = seg * 8 + e;
                int key = (d >> 2) & 7;
                int jsw = (j & 7) | (((j >> 3) ^ key) << 3);   // max 191 < VW
                Vt[d * VW + jsw] = v[e];
            }
        }
        __syncthreads();

        // S = Q.K^T (32 x 160)
        floatx4 sacc[5];
        #pragma unroll
        for (int t = 0; t < 5; t++) sacc[t] = (floatx4){0.f, 0.f, 0.f, 0.f};
        #pragma unroll
        for (int kb = 0; kb < 2; kb++) {
            bf16x8 a = *(bf16x8*)&Qs[rowHalf + lr][kb * 32 + lq * 8];
            #pragma unroll
            for (int t = 0; t < 5; t++) {
                bf16x8 bb = *(bf16x8*)&Ks[colBase + t * 16 + lr][kb * 32 + lq * 8];
                sacc[t] = __builtin_amdgcn_mfma_f32_16x16x32_bf16(a, bb, sacc[t], 0, 0, 0);
            }
        }

        const float srep = rep_scale[h];
        float l[5][4];
        float mx[4] = {NEG_BIG, NEG_BIG, NEG_BIG, NEG_BIG};
        #pragma unroll
        for (int t = 0; t < 5; t++) {
            int j = colBase + t * 16 + lr;
            int m = n0 - RR + j;
            #pragma unroll
            for (int r = 0; r < 4; r++) {
                int qi = rowHalf + lq * 4 + r;
                int relidx = qi + RR - j;
                bool valid = (relidx >= -RR) && (relidx <= RR) && (m >= 0) && (m < NN);
                float lv = sacc[t][r] * 0.125f + corrv[t][r] * srep +
                           relb[h - h0][relidx + 95];
                l[t][r] = valid ? lv : NEG_BIG;
                mx[r] = fmaxf(mx[r], l[t][r]);
            }
        }
        #pragma unroll
        for (int r = 0; r < 4; r++)
            #pragma unroll
            for (int mk = 1; mk <= 8; mk <<= 1)
                mx[r] = fmaxf(mx[r], __shfl_xor(mx[r], mk, 64));
        if (lr == 0) {
            #pragma unroll
            for (int r = 0; r < 4; r++) rmax2[rowHalf + lq * 4 + r][w & 1] = mx[r];
        }
        __syncthreads();

        float rm[4], sm[4];
        #pragma unroll
        for (int r = 0; r < 4; r++) {
            int row = rowHalf + lq * 4 + r;
            rm[r] = fmaxf(rmax2[row][0], rmax2[row][1]);
            sm[r] = 0.f;
        }
        #pragma unroll
        for (int t = 0; t < 5; t++) {
            int j = colBase + t * 16 + lr;
            #pragma unroll
            for (int r = 0; r < 4; r++) {
                float pv = __expf(l[t][r] - rm[r]);
                sm[r] += pv;
                Ps[rowHalf + lq * 4 + r][j] = (bf16)pv;
            }
        }
        #pragma unroll
        for (int r = 0; r < 4; r++)
            #pragma unroll
            for (int mk = 1; mk <= 8; mk <<= 1)
                sm[r] += __shfl_xor(sm[r], mk, 64);
        if (lr == 0) {
            #pragma unroll
            for (int r = 0; r < 4; r++) rsum2[rowHalf + lq * 4 + r][w & 1] = sm[r];
        }
        __syncthreads();

        // O = P.V (32 x 64), contraction over 160 band keys
        floatx4 oacc[2] = {(floatx4){0.f, 0.f, 0.f, 0.f}, (floatx4){0.f, 0.f, 0.f, 0.f}};
        #pragma unroll
        for (int kb = 0; kb < 5; kb++) {
            bf16x8 a = *(bf16x8*)&Ps[rowHalf + lr][kb * 32 + lq * 8];
            #pragma unroll
            for (int tt = 0; tt < 2; tt++) {
                int d = c2 + tt * 16 + lr;
                int key = (d >> 2) & 7;
                int jsw = (kb * 32 + lq * 8) ^ (key << 3);
                bf16x8 bb = *(bf16x8*)&Vt[d * VW + jsw];
                oacc[tt] = __builtin_amdgcn_mfma_f32_16x16x32_bf16(a, bb, oacc[tt], 0, 0, 0);
            }
        }
        #pragma unroll
        for (int r = 0; r < 4; r++) {
            int row = rowHalf + lq * 4 + r;
            float rinv = 1.f / (rsum2[row][0] + rsum2[row][1]);
            #pragma unroll
            for (int tt = 0; tt < 2; tt++) {
                upd[(size_t)(bN + n0 + row) * DD + h * HD + c2 + tt * 16 + lr] =
                    (bf16)(oacc[tt][r] * rinv);
            }
        }
        __syncthreads();   // protect Ks/Vt/Ps before next head's staging
    }
}

// ---------------------------------------------------------------- launch
// Inputs FLOAT32; OUTPUT FLOAT32.
extern "C" void kernel_launch(void* const* d_in, const int* in_sizes, int n_in,
                              void* d_out, int out_size, void* d_ws,
                              size_t ws_size, hipStream_t stream) {
    const float* nodes  = (const float*)d_in[0];
    const float* ln1_g  = (const float*)d_in[1];
    const float* ln1_b  = (const float*)d_in[2];
    const float* qkv_w  = (const float*)d_in[3];
    const float* qkv_b  = (const float*)d_in[4];
    const float* proj_w = (const float*)d_in[5];
    const float* proj_b = (const float*)d_in[6];
    const float* rep_s  = (const float*)d_in[7];
    const float* rel_b  = (const float*)d_in[8];
    const float* ln2_g  = (const float*)d_in[9];
    const float* ln2_b  = (const float*)d_in[10];
    const float* mlp_w1 = (const float*)d_in[11];
    const float* mlp_b1 = (const float*)d_in[12];
    const float* mlp_w2 = (const float*)d_in[13];
    const float* mlp_b2 = (const float*)d_in[14];

    char* p = (char*)d_ws;
    float* invn = (float*)p;            p += (size_t)1 << 20;
    bf16*  wq   = (bf16*)p;             p += (size_t)DD * D3 * 2;
    bf16*  wp   = (bf16*)p;             p += (size_t)DD * DD * 2;
    bf16*  w1   = (bf16*)p;             p += (size_t)DD * 2 * DD * 2;
    bf16*  w2   = (bf16*)p;             p += (size_t)2 * DD * DD * 2;
    bf16*  x    = (bf16*)p;             p += (size_t)BB * NN * DD * 2;
    bf16*  qkvb = (bf16*)p;             p += (size_t)BB * NN * D3 * 2;
    float* mid  = (float*)p;            p += (size_t)BB * NN * DD * 4;
    bf16*  y    = x;                // alias: x dead after attn_kernel
    bf16*  hgl  = qkvb;             // alias: qkvb dead after attn_kernel
    bf16*  upd  = (bf16*)d_out;     // scratch; consumed by gemm<1>, then
                                    // d_out fully rewritten (f32) by gemm<3>

    const int M = BB * NN;  // 4096

    cvt_kernel<<<DD * D3 / 1024, 256, 0, stream>>>(qkv_w, wq);
    cvt_kernel<<<DD * DD / 1024, 256, 0, stream>>>(proj_w, wp);
    cvt_kernel<<<DD * 2 * DD / 1024, 256, 0, stream>>>(mlp_w1, w1);
    cvt_kernel<<<2 * DD * DD / 1024, 256, 0, stream>>>(mlp_w2, w2);

    ln_kernel<true><<<M, 256, 0, stream>>>(nodes, ln1_g, ln1_b, x, invn);
    gemm_kernel<0><<<dim3(D3 / BN, M / BM), 256, 0, stream>>>(
        x, wq, qkv_b, nullptr, qkvb, M, D3, DD);
    attn_kernel<<<(NN / TQ) * 2 * BB, 256, 0, stream>>>(
        x, invn, qkvb, rep_s, rel_b, upd);
    gemm_kernel<1><<<dim3(DD / BN, M / BM), 256, 0, stream>>>(
        upd, wp, proj_b, nodes, mid, M, DD, DD);
    ln_kernel<false><<<M, 256, 0, stream>>>(mid, ln2_g, ln2_b, y, nullptr);
    gemm_kernel<2><<<dim3(2 * DD / BN, M / BM), 256, 0, stream>>>(
        y, w1, mlp_b1, nullptr, hgl, M, 2 * DD, DD);
    gemm_kernel<3><<<dim3(DD / BN, M / BM), 256, 0, stream>>>(
        hgl, w2, mlp_b2, mid, (float*)d_out, M, DD, 2 * DD);
}

// Round 8
// 204.799 us; speedup vs baseline: 2.4589x; 1.1454x over previous
//
#include <hip/hip_runtime.h>
#include <math.h>

typedef __bf16 bf16;
typedef __bf16 bf16x4 __attribute__((ext_vector_type(4)));
typedef __bf16 bf16x8 __attribute__((ext_vector_type(8)));
typedef float floatx4 __attribute__((ext_vector_type(4)));

#define BB 2
#define NN 2048
#define DD 512
#define HH 8
#define HD 64
#define RR 64
#define D3 1536
#define NEG_BIG (-1e30f)
#define TQ 32
#define TBAND 160
#define VW 200   // Vt row width: must be > max jsw = 191 (3-bit XOR swizzle)

// async global->LDS, 16B per lane; LDS dest must be wave-uniform base + lane*16
#define GL2LDS16(g, l)                                                        \
    __builtin_amdgcn_global_load_lds(                                         \
        (const __attribute__((address_space(1))) void*)(const void*)(g),      \
        (__attribute__((address_space(3))) void*)(void*)(l), 16, 0, 0)

// --------------------------------------------- f32 -> bf16 convert+TRANSPOSE
// W [K][N] f32 -> Wt [N][K] bf16.  64x64 tile per block, 256 threads.
__global__ __launch_bounds__(256) void cvt_t_kernel(
    const float* __restrict__ W, bf16* __restrict__ Wt, int K, int N) {
    __shared__ bf16 Ts[64][72];
    const int tid = threadIdx.x;
    const int n0 = blockIdx.x * 64, k0 = blockIdx.y * 64;
    #pragma unroll
    for (int i = 0; i < 4; i++) {
        int r = (tid >> 4) + i * 16;        // k within tile
        int c = (tid & 15) * 4;             // n within tile
        floatx4 v = *(const floatx4*)(W + (size_t)(k0 + r) * N + n0 + c);
        #pragma unroll
        for (int e = 0; e < 4; e++) Ts[r][c + e] = (bf16)v[e];
    }
    __syncthreads();
    #pragma unroll
    for (int i = 0; i < 4; i++) {
        int n = (tid >> 4) + i * 16;        // n within tile
        int k = (tid & 15) * 4;             // k within tile
        bf16x4 o;
        #pragma unroll
        for (int e = 0; e < 4; e++) o[e] = Ts[k + e][n];
        *(bf16x4*)(Wt + (size_t)(n0 + n) * K + k0 + k) = o;
    }
}

// ---------------------------------------------------------------- block reduce
__device__ inline float block_reduce_sum256(float v, float* sbuf) {
    const int tid = threadIdx.x;
    #pragma unroll
    for (int o = 32; o > 0; o >>= 1) v += __shfl_xor(v, o, 64);
    __syncthreads();
    if ((tid & 63) == 0) sbuf[tid >> 6] = v;
    __syncthreads();
    return sbuf[0] + sbuf[1] + sbuf[2] + sbuf[3];
}

// ---------------------------------------------------------------- LayerNorm
template <bool WANT_INV>
__global__ __launch_bounds__(256) void ln_kernel(
    const float* __restrict__ in, const float* __restrict__ gw,
    const float* __restrict__ bw, bf16* __restrict__ out,
    float* __restrict__ invnorm) {
    __shared__ float sbuf[4];
    const int row = blockIdx.x, tid = threadIdx.x;
    const int i0 = tid * 2;
    const float* ip = in + (size_t)row * DD;
    float v0 = ip[i0], v1 = ip[i0 + 1];
    float mean = block_reduce_sum256(v0 + v1, sbuf) * (1.f / DD);
    float d0 = v0 - mean, d1 = v1 - mean;
    float var = block_reduce_sum256(d0 * d0 + d1 * d1, sbuf) * (1.f / DD);
    float rs = rsqrtf(var + 1e-5f);
    float x0 = d0 * rs * gw[i0] + bw[i0];
    float x1 = d1 * rs * gw[i0 + 1] + bw[i0 + 1];
    out[(size_t)row * DD + i0] = (bf16)x0;
    out[(size_t)row * DD + i0 + 1] = (bf16)x1;
    if (WANT_INV) {
        float s2 = block_reduce_sum256(x0 * x0 + x1 * x1, sbuf);
        if (tid == 0) invnorm[row] = 1.f / fmaxf(sqrtf(s2), 1e-12f);
    }
}

// --------------------------------------------------- GEMM (MFMA, B^T input)
// C[M,N] = A[M,K](bf16) @ Bt[N,K](bf16)^T + bias(f32).  Tile 128 x BND, BK=32.
// Staging via global_load_lds width=16 (m97 pattern).  Epilogue by MODE:
//  0: store bf16 | 1: +resid f32->f32 | 2: exact gelu->bf16 | 3: +resid ->f32
template <int MODE, int BND>
__global__ __launch_bounds__(256) void gemm_bt(
    const bf16* __restrict__ A, const bf16* __restrict__ Bt,
    const float* __restrict__ bias, const float* __restrict__ resid,
    void* __restrict__ out, int M, int N, int K) {
    __shared__ __align__(16) bf16 As[128 * 32];
    __shared__ __align__(16) bf16 Bs[BND * 32];
    const int tid = threadIdx.x;
    const int w = tid >> 6, lane = tid & 63;
    const int rowBase = blockIdx.y * 128, colBase = blockIdx.x * BND;
    const int lr = lane & 15, lq = lane >> 4;
    // wave tiles: BND=128 -> 2x2 waves of 64x64 (MI=4); BND=64 -> 4x1 of 32x64
    constexpr int MI = (BND == 128) ? 4 : 2;
    const int wm = (BND == 128) ? (w >> 1) * 64 : w * 32;
    const int wn = (BND == 128) ? (w & 1) * 64 : 0;

    floatx4 acc[MI][4];
    #pragma unroll
    for (int i = 0; i < MI; i++)
        #pragma unroll
        for (int j = 0; j < 4; j++) acc[i][j] = (floatx4){0.f, 0.f, 0.f, 0.f};

    for (int k0 = 0; k0 < K; k0 += 32) {
        __syncthreads();
        #pragma unroll
        for (int i = 0; i < 2; i++) {          // A: 512 segs of 16B
            int s = (w * 2 + i) * 64 + lane;
            GL2LDS16(A + (size_t)(rowBase + (s >> 2)) * K + k0 + (s & 3) * 8,
                     As + s * 8);
        }
        #pragma unroll
        for (int i = 0; i < BND / 64; i++) {   // B: BND*4 segs of 16B
            int s = (w * (BND / 64) + i) * 64 + lane;
            GL2LDS16(Bt + (size_t)(colBase + (s >> 2)) * K + k0 + (s & 3) * 8,
                     Bs + s * 8);
        }
        __syncthreads();

        bf16x8 af[MI], bfr[4];
        #pragma unroll
        for (int i = 0; i < MI; i++)
            af[i] = *(bf16x8*)&As[(wm + i * 16 + lr) * 32 + lq * 8];
        #pragma unroll
        for (int j = 0; j < 4; j++)
            bfr[j] = *(bf16x8*)&Bs[(wn + j * 16 + lr) * 32 + lq * 8];
        #pragma unroll
        for (int i = 0; i < MI; i++)
            #pragma unroll
            for (int j = 0; j < 4; j++)
                acc[i][j] = __builtin_amdgcn_mfma_f32_16x16x32_bf16(
                    af[i], bfr[j], acc[i][j], 0, 0, 0);
    }

    #pragma unroll
    for (int i = 0; i < MI; i++) {
        #pragma unroll
        for (int j = 0; j < 4; j++) {
            #pragma unroll
            for (int r = 0; r < 4; r++) {
                int row = rowBase + wm + i * 16 + lq * 4 + r;
                int col = colBase + wn + j * 16 + lr;
                size_t idx = (size_t)row * N + col;
                float v = acc[i][j][r] + bias[col];
                if (MODE == 0) {
                    ((bf16*)out)[idx] = (bf16)v;
                } else if (MODE == 1) {
                    ((float*)out)[idx] = v + resid[idx];
                } else if (MODE == 2) {
                    float g = 0.5f * v * (1.f + erff(v * 0.70710678118654752f));
                    ((bf16*)out)[idx] = (bf16)g;
                } else {
                    ((float*)out)[idx] = v + resid[idx];
                }
            }
        }
    }
}

// ---------------------------------------------------------------- attention
// Tiled MFMA version. Block: TQ=32 queries, band of 160 keys, 4 of 8 heads.
__global__ __launch_bounds__(256) void attn_kernel(
    const bf16* __restrict__ x, const float* __restrict__ invnorm,
    const bf16* __restrict__ qkv, const float* __restrict__ rep_scale,
    const float* __restrict__ rel_bias, bf16* __restrict__ upd) {
    __shared__ __align__(16) bf16 Qs[TQ][72];
    __shared__ __align__(16) bf16 Ks[TBAND][72];
    __shared__ __align__(16) bf16 Vt[64 * VW];
    __shared__ __align__(16) bf16 Ps[TQ][168];
    __shared__ float relb[4][192];
    __shared__ float invb[TBAND];
    __shared__ float rmax2[TQ][2];
    __shared__ float rsum2[TQ][2];

    const int tid = threadIdx.x;
    const int bid = blockIdx.x;
    const int b = bid & 1;
    const int h0 = ((bid >> 1) & 1) * 4;
    const int n0 = (bid >> 2) * TQ;
    const int bN = b * NN;

    const int w = tid >> 6, lane = tid & 63;
    const int lr = lane & 15, lq = lane >> 4;
    const int rowHalf = (w >> 1) * 16;
    const int colBase = (w & 1) * 80;
    const int c2 = (w & 1) * 32;

    if (tid < TBAND) {
        int mc = min(max(n0 - RR + tid, 0), NN - 1);
        invb[tid] = invnorm[bN + mc];
    }
    for (int idx = tid; idx < 4 * 191; idx += 256) {
        int hh = idx / 191, dh = idx - hh * 191;
        relb[hh][dh] = rel_bias[(size_t)(dh + (NN - 1 - 95)) * HH + h0 + hh];
    }

    // ---- pass 1: corr accumulation over 8 chunks of 64 dims
    floatx4 cacc[5];
    #pragma unroll
    for (int t = 0; t < 5; t++) cacc[t] = (floatx4){0.f, 0.f, 0.f, 0.f};

    for (int c = 0; c < 8; c++) {
        __syncthreads();
        #pragma unroll
        for (int i = 0; i < 5; i++) {
            int s = i * 256 + tid;
            int j = s >> 3, seg = s & 7;
            int mc = min(max(n0 - RR + j, 0), NN - 1);
            *(bf16x8*)&Ks[j][seg * 8] =
                *(const bf16x8*)(x + (size_t)(bN + mc) * DD + c * 64 + seg * 8);
        }
        __syncthreads();
        #pragma unroll
        for (int kb = 0; kb < 2; kb++) {
            bf16x8 a = *(bf16x8*)&Ks[64 + rowHalf + lr][kb * 32 + lq * 8];
            #pragma unroll
            for (int t = 0; t < 5; t++) {
                bf16x8 bb = *(bf16x8*)&Ks[colBase + t * 16 + lr][kb * 32 + lq * 8];
                cacc[t] = __builtin_amdgcn_mfma_f32_16x16x32_bf16(a, bb, cacc[t], 0, 0, 0);
            }
        }
    }
    __syncthreads();

    float corrv[5][4];
    {
        float invq[4];
        #pragma unroll
        for (int r = 0; r < 4; r++) invq[r] = invb[64 + rowHalf + lq * 4 + r];
        #pragma unroll
        for (int t = 0; t < 5; t++) {
            float invk = invb[colBase + t * 16 + lr];
            #pragma unroll
            for (int r = 0; r < 4; r++) corrv[t][r] = cacc[t][r] * invq[r] * invk;
        }
    }

    // ---- pass 2: per head
    for (int h = h0; h < h0 + 4; h++) {
        {
            int row = tid >> 3, seg = tid & 7;
            *(bf16x8*)&Qs[row][seg * 8] =
                *(const bf16x8*)(qkv + (size_t)(bN + n0 + row) * D3 + h * HD + seg * 8);
        }
        #pragma unroll
        for (int i = 0; i < 5; i++) {
            int s = i * 256 + tid;
            int j = s >> 3, seg = s & 7;
            int mc = min(max(n0 - RR + j, 0), NN - 1);
            *(bf16x8*)&Ks[j][seg * 8] =
                *(const bf16x8*)(qkv + (size_t)(bN + mc) * D3 + DD + h * HD + seg * 8);
            bf16x8 v = *(const bf16x8*)(qkv + (size_t)(bN + mc) * D3 + 2 * DD + h * HD + seg * 8);
            #pragma unroll
            for (int e = 0; e < 8; e++) {
                int d = seg * 8 + e;
                int key = (d >> 2) & 7;
                int jsw = (j & 7) | (((j >> 3) ^ key) << 3);   // max 191 < VW
                Vt[d * VW + jsw] = v[e];
            }
        }
        __syncthreads();

        floatx4 sacc[5];
        #pragma unroll
        for (int t = 0; t < 5; t++) sacc[t] = (floatx4){0.f, 0.f, 0.f, 0.f};
        #pragma unroll
        for (int kb = 0; kb < 2; kb++) {
            bf16x8 a = *(bf16x8*)&Qs[rowHalf + lr][kb * 32 + lq * 8];
            #pragma unroll
            for (int t = 0; t < 5; t++) {
                bf16x8 bb = *(bf16x8*)&Ks[colBase + t * 16 + lr][kb * 32 + lq * 8];
                sacc[t] = __builtin_amdgcn_mfma_f32_16x16x32_bf16(a, bb, sacc[t], 0, 0, 0);
            }
        }

        const float srep = rep_scale[h];
        float l[5][4];
        float mx[4] = {NEG_BIG, NEG_BIG, NEG_BIG, NEG_BIG};
        #pragma unroll
        for (int t = 0; t < 5; t++) {
            int j = colBase + t * 16 + lr;
            int m = n0 - RR + j;
            #pragma unroll
            for (int r = 0; r < 4; r++) {
                int qi = rowHalf + lq * 4 + r;
                int relidx = qi + RR - j;
                bool valid = (relidx >= -RR) && (relidx <= RR) && (m >= 0) && (m < NN);
                float lv = sacc[t][r] * 0.125f + corrv[t][r] * srep +
                           relb[h - h0][relidx + 95];
                l[t][r] = valid ? lv : NEG_BIG;
                mx[r] = fmaxf(mx[r], l[t][r]);
            }
        }
        #pragma unroll
        for (int r = 0; r < 4; r++)
            #pragma unroll
            for (int mk = 1; mk <= 8; mk <<= 1)
                mx[r] = fmaxf(mx[r], __shfl_xor(mx[r], mk, 64));
        if (lr == 0) {
            #pragma unroll
            for (int r = 0; r < 4; r++) rmax2[rowHalf + lq * 4 + r][w & 1] = mx[r];
        }
        __syncthreads();

        float rm[4], sm[4];
        #pragma unroll
        for (int r = 0; r < 4; r++) {
            int row = rowHalf + lq * 4 + r;
            rm[r] = fmaxf(rmax2[row][0], rmax2[row][1]);
            sm[r] = 0.f;
        }
        #pragma unroll
        for (int t = 0; t < 5; t++) {
            int j = colBase + t * 16 + lr;
            #pragma unroll
            for (int r = 0; r < 4; r++) {
                float pv = __expf(l[t][r] - rm[r]);
                sm[r] += pv;
                Ps[rowHalf + lq * 4 + r][j] = (bf16)pv;
            }
        }
        #pragma unroll
        for (int r = 0; r < 4; r++)
            #pragma unroll
            for (int mk = 1; mk <= 8; mk <<= 1)
                sm[r] += __shfl_xor(sm[r], mk, 64);
        if (lr == 0) {
            #pragma unroll
            for (int r = 0; r < 4; r++) rsum2[rowHalf + lq * 4 + r][w & 1] = sm[r];
        }
        __syncthreads();

        floatx4 oacc[2] = {(floatx4){0.f, 0.f, 0.f, 0.f}, (floatx4){0.f, 0.f, 0.f, 0.f}};
        #pragma unroll
        for (int kb = 0; kb < 5; kb++) {
            bf16x8 a = *(bf16x8*)&Ps[rowHalf + lr][kb * 32 + lq * 8];
            #pragma unroll
            for (int tt = 0; tt < 2; tt++) {
                int d = c2 + tt * 16 + lr;
                int key = (d >> 2) & 7;
                int jsw = (kb * 32 + lq * 8) ^ (key << 3);
                bf16x8 bb = *(bf16x8*)&Vt[d * VW + jsw];
                oacc[tt] = __builtin_amdgcn_mfma_f32_16x16x32_bf16(a, bb, oacc[tt], 0, 0, 0);
            }
        }
        #pragma unroll
        for (int r = 0; r < 4; r++) {
            int row = rowHalf + lq * 4 + r;
            float rinv = 1.f / (rsum2[row][0] + rsum2[row][1]);
            #pragma unroll
            for (int tt = 0; tt < 2; tt++) {
                upd[(size_t)(bN + n0 + row) * DD + h * HD + c2 + tt * 16 + lr] =
                    (bf16)(oacc[tt][r] * rinv);
            }
        }
        __syncthreads();
    }
}

// ---------------------------------------------------------------- launch
// Inputs FLOAT32; OUTPUT FLOAT32.
extern "C" void kernel_launch(void* const* d_in, const int* in_sizes, int n_in,
                              void* d_out, int out_size, void* d_ws,
                              size_t ws_size, hipStream_t stream) {
    const float* nodes  = (const float*)d_in[0];
    const float* ln1_g  = (const float*)d_in[1];
    const float* ln1_b  = (const float*)d_in[2];
    const float* qkv_w  = (const float*)d_in[3];
    const float* qkv_b  = (const float*)d_in[4];
    const float* proj_w = (const float*)d_in[5];
    const float* proj_b = (const float*)d_in[6];
    const float* rep_s  = (const float*)d_in[7];
    const float* rel_b  = (const float*)d_in[8];
    const float* ln2_g  = (const float*)d_in[9];
    const float* ln2_b  = (const float*)d_in[10];
    const float* mlp_w1 = (const float*)d_in[11];
    const float* mlp_b1 = (const float*)d_in[12];
    const float* mlp_w2 = (const float*)d_in[13];
    const float* mlp_b2 = (const float*)d_in[14];

    char* p = (char*)d_ws;
    float* invn = (float*)p;            p += (size_t)1 << 20;
    bf16*  wqt  = (bf16*)p;             p += (size_t)DD * D3 * 2;       // [1536][512]
    bf16*  wpt  = (bf16*)p;             p += (size_t)DD * DD * 2;       // [512][512]
    bf16*  w1t  = (bf16*)p;             p += (size_t)DD * 2 * DD * 2;   // [1024][512]
    bf16*  w2t  = (bf16*)p;             p += (size_t)2 * DD * DD * 2;   // [512][1024]
    bf16*  x    = (bf16*)p;             p += (size_t)BB * NN * DD * 2;
    bf16*  qkvb = (bf16*)p;             p += (size_t)BB * NN * D3 * 2;
    float* mid  = (float*)p;            p += (size_t)BB * NN * DD * 4;
    bf16*  y    = x;                // alias: x dead after attn_kernel
    bf16*  hgl  = qkvb;             // alias: qkvb dead after attn_kernel
    bf16*  upd  = (bf16*)d_out;     // scratch; consumed by gemm<1>, then
                                    // d_out fully rewritten (f32) by gemm<3>

    const int M = BB * NN;  // 4096

    cvt_t_kernel<<<dim3(D3 / 64, DD / 64), 256, 0, stream>>>(qkv_w, wqt, DD, D3);
    cvt_t_kernel<<<dim3(DD / 64, DD / 64), 256, 0, stream>>>(proj_w, wpt, DD, DD);
    cvt_t_kernel<<<dim3(2 * DD / 64, DD / 64), 256, 0, stream>>>(mlp_w1, w1t, DD, 2 * DD);
    cvt_t_kernel<<<dim3(DD / 64, 2 * DD / 64), 256, 0, stream>>>(mlp_w2, w2t, 2 * DD, DD);

    ln_kernel<true><<<M, 256, 0, stream>>>(nodes, ln1_g, ln1_b, x, invn);
    gemm_bt<0, 128><<<dim3(D3 / 128, M / 128), 256, 0, stream>>>(
        x, wqt, qkv_b, nullptr, qkvb, M, D3, DD);
    attn_kernel<<<(NN / TQ) * 2 * BB, 256, 0, stream>>>(
        x, invn, qkvb, rep_s, rel_b, upd);
    gemm_bt<1, 64><<<dim3(DD / 64, M / 128), 256, 0, stream>>>(
        upd, wpt, proj_b, nodes, mid, M, DD, DD);
    ln_kernel<false><<<M, 256, 0, stream>>>(mid, ln2_g, ln2_b, y, nullptr);
    gemm_bt<2, 128><<<dim3(2 * DD / 128, M / 128), 256, 0, stream>>>(
        y, w1t, mlp_b1, nullptr, hgl, M, 2 * DD, DD);
    gemm_bt<3, 64><<<dim3(DD / 64, M / 128), 256, 0, stream>>>(
        hgl, w2t, mlp_b2, mid, (float*)d_out, M, DD, 2 * DD);
}

// Round 9
// 182.832 us; speedup vs baseline: 2.7543x; 1.1201x over previous
//
#include <hip/hip_runtime.h>
#include <math.h>

typedef __bf16 bf16;
typedef __bf16 bf16x4 __attribute__((ext_vector_type(4)));
typedef __bf16 bf16x8 __attribute__((ext_vector_type(8)));
typedef float floatx4 __attribute__((ext_vector_type(4)));

#define BB 2
#define NN 2048
#define DD 512
#define HH 8
#define HD 64
#define RR 64
#define D3 1536
#define NEG_BIG (-1e30f)
#define TQ 32
#define TBAND 160
#define VW 200   // Vt row width: must be > max jsw = 191 (3-bit XOR swizzle)

// async global->LDS, 16B per lane; LDS dest must be wave-uniform base + lane*16
#define GL2LDS16(g, l)                                                        \
    __builtin_amdgcn_global_load_lds(                                         \
        (const __attribute__((address_space(1))) void*)(const void*)(g),      \
        (__attribute__((address_space(3))) void*)(void*)(l), 16, 0, 0)

// --------------------------------------------- f32 -> bf16 convert+TRANSPOSE
// W [K][N] f32 -> Wt [N][K] bf16.  64x64 tile per block, 256 threads.
__global__ __launch_bounds__(256) void cvt_t_kernel(
    const float* __restrict__ W, bf16* __restrict__ Wt, int K, int N) {
    __shared__ bf16 Ts[64][72];
    const int tid = threadIdx.x;
    const int n0 = blockIdx.x * 64, k0 = blockIdx.y * 64;
    #pragma unroll
    for (int i = 0; i < 4; i++) {
        int r = (tid >> 4) + i * 16;        // k within tile
        int c = (tid & 15) * 4;             // n within tile
        floatx4 v = *(const floatx4*)(W + (size_t)(k0 + r) * N + n0 + c);
        #pragma unroll
        for (int e = 0; e < 4; e++) Ts[r][c + e] = (bf16)v[e];
    }
    __syncthreads();
    #pragma unroll
    for (int i = 0; i < 4; i++) {
        int n = (tid >> 4) + i * 16;        // n within tile
        int k = (tid & 15) * 4;             // k within tile
        bf16x4 o;
        #pragma unroll
        for (int e = 0; e < 4; e++) o[e] = Ts[k + e][n];
        *(bf16x4*)(Wt + (size_t)(n0 + n) * K + k0 + k) = o;
    }
}

// ---------------------------------------------------------------- block reduce
__device__ inline float block_reduce_sum256(float v, float* sbuf) {
    const int tid = threadIdx.x;
    #pragma unroll
    for (int o = 32; o > 0; o >>= 1) v += __shfl_xor(v, o, 64);
    __syncthreads();
    if ((tid & 63) == 0) sbuf[tid >> 6] = v;
    __syncthreads();
    return sbuf[0] + sbuf[1] + sbuf[2] + sbuf[3];
}

// ---------------------------------------------------------------- LayerNorm
template <bool WANT_INV>
__global__ __launch_bounds__(256) void ln_kernel(
    const float* __restrict__ in, const float* __restrict__ gw,
    const float* __restrict__ bw, bf16* __restrict__ out,
    float* __restrict__ invnorm) {
    __shared__ float sbuf[4];
    const int row = blockIdx.x, tid = threadIdx.x;
    const int i0 = tid * 2;
    const float* ip = in + (size_t)row * DD;
    float v0 = ip[i0], v1 = ip[i0 + 1];
    float mean = block_reduce_sum256(v0 + v1, sbuf) * (1.f / DD);
    float d0 = v0 - mean, d1 = v1 - mean;
    float var = block_reduce_sum256(d0 * d0 + d1 * d1, sbuf) * (1.f / DD);
    float rs = rsqrtf(var + 1e-5f);
    float x0 = d0 * rs * gw[i0] + bw[i0];
    float x1 = d1 * rs * gw[i0 + 1] + bw[i0 + 1];
    out[(size_t)row * DD + i0] = (bf16)x0;
    out[(size_t)row * DD + i0 + 1] = (bf16)x1;
    if (WANT_INV) {
        float s2 = block_reduce_sum256(x0 * x0 + x1 * x1, sbuf);
        if (tid == 0) invnorm[row] = 1.f / fmaxf(sqrtf(s2), 1e-12f);
    }
}

// --------------------------------------------------- GEMM (MFMA, B^T input)
// C[M,N] = A[M,K](bf16) @ Bt[N,K](bf16)^T + bias(f32).
// 64x64 tile, BK=64, DOUBLE-BUFFERED LDS (stage k+1 after barrier, compute k).
// LDS layout XOR-swizzled at 16B-granule level: data (row, k8) stored at
// granule row*8 + (k8 ^ (row&7)) -- keeps global_load_lds's uniform+lane*16
// dest while making fragment ds_read_b128 conflict-free (2-way max).
//  0: store bf16 | 1: +resid f32->f32 | 2: exact gelu->bf16 | 3: +resid ->f32
template <int MODE>
__global__ __launch_bounds__(256) void gemm_bt(
    const bf16* __restrict__ A, const bf16* __restrict__ Bt,
    const float* __restrict__ bias, const float* __restrict__ resid,
    void* __restrict__ out, int M, int N, int K) {
    __shared__ __align__(16) bf16 As[2][64 * 64];
    __shared__ __align__(16) bf16 Bs[2][64 * 64];
    const int tid = threadIdx.x;
    const int w = tid >> 6, lane = tid & 63;
    const int lr = lane & 15, lq = lane >> 4;
    const int rowBase = blockIdx.y * 64, colBase = blockIdx.x * 64;
    const int wm = (w >> 1) * 32, wn = (w & 1) * 32;   // wave = 32x32 subtile

    floatx4 acc[2][2];
    #pragma unroll
    for (int i = 0; i < 2; i++)
        #pragma unroll
        for (int j = 0; j < 2; j++) acc[i][j] = (floatx4){0.f, 0.f, 0.f, 0.f};

    // staging: 512 granules of 16B per 64x64 tile = 2 rounds of 256 threads
    auto stage = [&](int buf, int k0) {
        #pragma unroll
        for (int i = 0; i < 2; i++) {
            int g = i * 256 + tid;
            int row = g >> 3, k8 = (g & 7) ^ (row & 7);
            GL2LDS16(A + (size_t)(rowBase + row) * K + k0 + k8 * 8,
                     &As[buf][g * 8]);
        }
        #pragma unroll
        for (int i = 0; i < 2; i++) {
            int g = i * 256 + tid;
            int row = g >> 3, k8 = (g & 7) ^ (row & 7);
            GL2LDS16(Bt + (size_t)(colBase + row) * K + k0 + k8 * 8,
                     &Bs[buf][g * 8]);
        }
    };

    const int nsteps = K >> 6;
    stage(0, 0);
    for (int s = 0; s < nsteps; s++) {
        __syncthreads();                       // drains vmcnt(0): buf s&1 ready
        if (s + 1 < nsteps) stage((s + 1) & 1, (s + 1) * 64);
        const int buf = s & 1;
        #pragma unroll
        for (int kb = 0; kb < 2; kb++) {
            bf16x8 af[2], bfr[2];
            #pragma unroll
            for (int i = 0; i < 2; i++) {
                int row = wm + i * 16 + lr;
                int g = row * 8 + ((kb * 4 + lq) ^ (row & 7));
                af[i] = *(bf16x8*)&As[buf][g * 8];
            }
            #pragma unroll
            for (int j = 0; j < 2; j++) {
                int row = wn + j * 16 + lr;
                int g = row * 8 + ((kb * 4 + lq) ^ (row & 7));
                bfr[j] = *(bf16x8*)&Bs[buf][g * 8];
            }
            #pragma unroll
            for (int i = 0; i < 2; i++)
                #pragma unroll
                for (int j = 0; j < 2; j++)
                    acc[i][j] = __builtin_amdgcn_mfma_f32_16x16x32_bf16(
                        af[i], bfr[j], acc[i][j], 0, 0, 0);
        }
    }

    #pragma unroll
    for (int i = 0; i < 2; i++) {
        #pragma unroll
        for (int j = 0; j < 2; j++) {
            #pragma unroll
            for (int r = 0; r < 4; r++) {
                int row = rowBase + wm + i * 16 + lq * 4 + r;
                int col = colBase + wn + j * 16 + lr;
                size_t idx = (size_t)row * N + col;
                float v = acc[i][j][r] + bias[col];
                if (MODE == 0) {
                    ((bf16*)out)[idx] = (bf16)v;
                } else if (MODE == 1) {
                    ((float*)out)[idx] = v + resid[idx];
                } else if (MODE == 2) {
                    float g = 0.5f * v * (1.f + erff(v * 0.70710678118654752f));
                    ((bf16*)out)[idx] = (bf16)g;
                } else {
                    ((float*)out)[idx] = v + resid[idx];
                }
            }
        }
    }
}

// ---------------------------------------------------------------- attention
// Tiled MFMA version. Block: TQ=32 queries, band of 160 keys, 4 of 8 heads.
__global__ __launch_bounds__(256) void attn_kernel(
    const bf16* __restrict__ x, const float* __restrict__ invnorm,
    const bf16* __restrict__ qkv, const float* __restrict__ rep_scale,
    const float* __restrict__ rel_bias, bf16* __restrict__ upd) {
    __shared__ __align__(16) bf16 Qs[TQ][72];
    __shared__ __align__(16) bf16 Ks[TBAND][72];
    __shared__ __align__(16) bf16 Vt[64 * VW];
    __shared__ __align__(16) bf16 Ps[TQ][168];
    __shared__ float relb[4][192];
    __shared__ float invb[TBAND];
    __shared__ float rmax2[TQ][2];
    __shared__ float rsum2[TQ][2];

    const int tid = threadIdx.x;
    const int bid = blockIdx.x;
    const int b = bid & 1;
    const int h0 = ((bid >> 1) & 1) * 4;
    const int n0 = (bid >> 2) * TQ;
    const int bN = b * NN;

    const int w = tid >> 6, lane = tid & 63;
    const int lr = lane & 15, lq = lane >> 4;
    const int rowHalf = (w >> 1) * 16;
    const int colBase = (w & 1) * 80;
    const int c2 = (w & 1) * 32;

    if (tid < TBAND) {
        int mc = min(max(n0 - RR + tid, 0), NN - 1);
        invb[tid] = invnorm[bN + mc];
    }
    for (int idx = tid; idx < 4 * 191; idx += 256) {
        int hh = idx / 191, dh = idx - hh * 191;
        relb[hh][dh] = rel_bias[(size_t)(dh + (NN - 1 - 95)) * HH + h0 + hh];
    }

    // ---- pass 1: corr accumulation over 8 chunks of 64 dims
    floatx4 cacc[5];
    #pragma unroll
    for (int t = 0; t < 5; t++) cacc[t] = (floatx4){0.f, 0.f, 0.f, 0.f};

    for (int c = 0; c < 8; c++) {
        __syncthreads();
        #pragma unroll
        for (int i = 0; i < 5; i++) {
            int s = i * 256 + tid;
            int j = s >> 3, seg = s & 7;
            int mc = min(max(n0 - RR + j, 0), NN - 1);
            *(bf16x8*)&Ks[j][seg * 8] =
                *(const bf16x8*)(x + (size_t)(bN + mc) * DD + c * 64 + seg * 8);
        }
        __syncthreads();
        #pragma unroll
        for (int kb = 0; kb < 2; kb++) {
            bf16x8 a = *(bf16x8*)&Ks[64 + rowHalf + lr][kb * 32 + lq * 8];
            #pragma unroll
            for (int t = 0; t < 5; t++) {
                bf16x8 bb = *(bf16x8*)&Ks[colBase + t * 16 + lr][kb * 32 + lq * 8];
                cacc[t] = __builtin_amdgcn_mfma_f32_16x16x32_bf16(a, bb, cacc[t], 0, 0, 0);
            }
        }
    }
    __syncthreads();

    float corrv[5][4];
    {
        float invq[4];
        #pragma unroll
        for (int r = 0; r < 4; r++) invq[r] = invb[64 + rowHalf + lq * 4 + r];
        #pragma unroll
        for (int t = 0; t < 5; t++) {
            float invk = invb[colBase + t * 16 + lr];
            #pragma unroll
            for (int r = 0; r < 4; r++) corrv[t][r] = cacc[t][r] * invq[r] * invk;
        }
    }

    // ---- pass 2: per head
    for (int h = h0; h < h0 + 4; h++) {
        {
            int row = tid >> 3, seg = tid & 7;
            *(bf16x8*)&Qs[row][seg * 8] =
                *(const bf16x8*)(qkv + (size_t)(bN + n0 + row) * D3 + h * HD + seg * 8);
        }
        #pragma unroll
        for (int i = 0; i < 5; i++) {
            int s = i * 256 + tid;
            int j = s >> 3, seg = s & 7;
            int mc = min(max(n0 - RR + j, 0), NN - 1);
            *(bf16x8*)&Ks[j][seg * 8] =
                *(const bf16x8*)(qkv + (size_t)(bN + mc) * D3 + DD + h * HD + seg * 8);
            bf16x8 v = *(const bf16x8*)(qkv + (size_t)(bN + mc) * D3 + 2 * DD + h * HD + seg * 8);
            #pragma unroll
            for (int e = 0; e < 8; e++) {
                int d = seg * 8 + e;
                int key = (d >> 2) & 7;
                int jsw = (j & 7) | (((j >> 3) ^ key) << 3);   // max 191 < VW
                Vt[d * VW + jsw] = v[e];
            }
        }
        __syncthreads();

        floatx4 sacc[5];
        #pragma unroll
        for (int t = 0; t < 5; t++) sacc[t] = (floatx4){0.f, 0.f, 0.f, 0.f};
        #pragma unroll
        for (int kb = 0; kb < 2; kb++) {
            bf16x8 a = *(bf16x8*)&Qs[rowHalf + lr][kb * 32 + lq * 8];
            #pragma unroll
            for (int t = 0; t < 5; t++) {
                bf16x8 bb = *(bf16x8*)&Ks[colBase + t * 16 + lr][kb * 32 + lq * 8];
                sacc[t] = __builtin_amdgcn_mfma_f32_16x16x32_bf16(a, bb, sacc[t], 0, 0, 0);
            }
        }

        const float srep = rep_scale[h];
        float l[5][4];
        float mx[4] = {NEG_BIG, NEG_BIG, NEG_BIG, NEG_BIG};
        #pragma unroll
        for (int t = 0; t < 5; t++) {
            int j = colBase + t * 16 + lr;
            int m = n0 - RR + j;
            #pragma unroll
            for (int r = 0; r < 4; r++) {
                int qi = rowHalf + lq * 4 + r;
                int relidx = qi + RR - j;
                bool valid = (relidx >= -RR) && (relidx <= RR) && (m >= 0) && (m < NN);
                float lv = sacc[t][r] * 0.125f + corrv[t][r] * srep +
                           relb[h - h0][relidx + 95];
                l[t][r] = valid ? lv : NEG_BIG;
                mx[r] = fmaxf(mx[r], l[t][r]);
            }
        }
        #pragma unroll
        for (int r = 0; r < 4; r++)
            #pragma unroll
            for (int mk = 1; mk <= 8; mk <<= 1)
                mx[r] = fmaxf(mx[r], __shfl_xor(mx[r], mk, 64));
        if (lr == 0) {
            #pragma unroll
            for (int r = 0; r < 4; r++) rmax2[rowHalf + lq * 4 + r][w & 1] = mx[r];
        }
        __syncthreads();

        float rm[4], sm[4];
        #pragma unroll
        for (int r = 0; r < 4; r++) {
            int row = rowHalf + lq * 4 + r;
            rm[r] = fmaxf(rmax2[row][0], rmax2[row][1]);
            sm[r] = 0.f;
        }
        #pragma unroll
        for (int t = 0; t < 5; t++) {
            int j = colBase + t * 16 + lr;
            #pragma unroll
            for (int r = 0; r < 4; r++) {
                float pv = __expf(l[t][r] - rm[r]);
                sm[r] += pv;
                Ps[rowHalf + lq * 4 + r][j] = (bf16)pv;
            }
        }
        #pragma unroll
        for (int r = 0; r < 4; r++)
            #pragma unroll
            for (int mk = 1; mk <= 8; mk <<= 1)
                sm[r] += __shfl_xor(sm[r], mk, 64);
        if (lr == 0) {
            #pragma unroll
            for (int r = 0; r < 4; r++) rsum2[rowHalf + lq * 4 + r][w & 1] = sm[r];
        }
        __syncthreads();

        floatx4 oacc[2] = {(floatx4){0.f, 0.f, 0.f, 0.f}, (floatx4){0.f, 0.f, 0.f, 0.f}};
        #pragma unroll
        for (int kb = 0; kb < 5; kb++) {
            bf16x8 a = *(bf16x8*)&Ps[rowHalf + lr][kb * 32 + lq * 8];
            #pragma unroll
            for (int tt = 0; tt < 2; tt++) {
                int d = c2 + tt * 16 + lr;
                int key = (d >> 2) & 7;
                int jsw = (kb * 32 + lq * 8) ^ (key << 3);
                bf16x8 bb = *(bf16x8*)&Vt[d * VW + jsw];
                oacc[tt] = __builtin_amdgcn_mfma_f32_16x16x32_bf16(a, bb, oacc[tt], 0, 0, 0);
            }
        }
        #pragma unroll
        for (int r = 0; r < 4; r++) {
            int row = rowHalf + lq * 4 + r;
            float rinv = 1.f / (rsum2[row][0] + rsum2[row][1]);
            #pragma unroll
            for (int tt = 0; tt < 2; tt++) {
                upd[(size_t)(bN + n0 + row) * DD + h * HD + c2 + tt * 16 + lr] =
                    (bf16)(oacc[tt][r] * rinv);
            }
        }
        __syncthreads();
    }
}

// ---------------------------------------------------------------- launch
// Inputs FLOAT32; OUTPUT FLOAT32.
extern "C" void kernel_launch(void* const* d_in, const int* in_sizes, int n_in,
                              void* d_out, int out_size, void* d_ws,
                              size_t ws_size, hipStream_t stream) {
    const float* nodes  = (const float*)d_in[0];
    const float* ln1_g  = (const float*)d_in[1];
    const float* ln1_b  = (const float*)d_in[2];
    const float* qkv_w  = (const float*)d_in[3];
    const float* qkv_b  = (const float*)d_in[4];
    const float* proj_w = (const float*)d_in[5];
    const float* proj_b = (const float*)d_in[6];
    const float* rep_s  = (const float*)d_in[7];
    const float* rel_b  = (const float*)d_in[8];
    const float* ln2_g  = (const float*)d_in[9];
    const float* ln2_b  = (const float*)d_in[10];
    const float* mlp_w1 = (const float*)d_in[11];
    const float* mlp_b1 = (const float*)d_in[12];
    const float* mlp_w2 = (const float*)d_in[13];
    const float* mlp_b2 = (const float*)d_in[14];

    char* p = (char*)d_ws;
    float* invn = (float*)p;            p += (size_t)1 << 20;
    bf16*  wqt  = (bf16*)p;             p += (size_t)DD * D3 * 2;       // [1536][512]
    bf16*  wpt  = (bf16*)p;             p += (size_t)DD * DD * 2;       // [512][512]
    bf16*  w1t  = (bf16*)p;             p += (size_t)DD * 2 * DD * 2;   // [1024][512]
    bf16*  w2t  = (bf16*)p;             p += (size_t)2 * DD * DD * 2;   // [512][1024]
    bf16*  x    = (bf16*)p;             p += (size_t)BB * NN * DD * 2;
    bf16*  qkvb = (bf16*)p;             p += (size_t)BB * NN * D3 * 2;
    float* mid  = (float*)p;            p += (size_t)BB * NN * DD * 4;
    bf16*  y    = x;                // alias: x dead after attn_kernel
    bf16*  hgl  = qkvb;             // alias: qkvb dead after attn_kernel
    bf16*  upd  = (bf16*)d_out;     // scratch; consumed by gemm<1>, then
                                    // d_out fully rewritten (f32) by gemm<3>

    const int M = BB * NN;  // 4096

    cvt_t_kernel<<<dim3(D3 / 64, DD / 64), 256, 0, stream>>>(qkv_w, wqt, DD, D3);
    cvt_t_kernel<<<dim3(DD / 64, DD / 64), 256, 0, stream>>>(proj_w, wpt, DD, DD);
    cvt_t_kernel<<<dim3(2 * DD / 64, DD / 64), 256, 0, stream>>>(mlp_w1, w1t, DD, 2 * DD);
    cvt_t_kernel<<<dim3(DD / 64, 2 * DD / 64), 256, 0, stream>>>(mlp_w2, w2t, 2 * DD, DD);

    ln_kernel<true><<<M, 256, 0, stream>>>(nodes, ln1_g, ln1_b, x, invn);
    gemm_bt<0><<<dim3(D3 / 64, M / 64), 256, 0, stream>>>(
        x, wqt, qkv_b, nullptr, qkvb, M, D3, DD);
    attn_kernel<<<(NN / TQ) * 2 * BB, 256, 0, stream>>>(
        x, invn, qkvb, rep_s, rel_b, upd);
    gemm_bt<1><<<dim3(DD / 64, M / 64), 256, 0, stream>>>(
        upd, wpt, proj_b, nodes, mid, M, DD, DD);
    ln_kernel<false><<<M, 256, 0, stream>>>(mid, ln2_g, ln2_b, y, nullptr);
    gemm_bt<2><<<dim3(2 * DD / 64, M / 64), 256, 0, stream>>>(
        y, w1t, mlp_b1, nullptr, hgl, M, 2 * DD, DD);
    gemm_bt<3><<<dim3(DD / 64, M / 64), 256, 0, stream>>>(
        hgl, w2t, mlp_b2, mid, (float*)d_out, M, DD, 2 * DD);
}

// Round 10
// 179.174 us; speedup vs baseline: 2.8105x; 1.0204x over previous
//
#include <hip/hip_runtime.h>
#include <math.h>

typedef __bf16 bf16;
typedef __bf16 bf16x4 __attribute__((ext_vector_type(4)));
typedef __bf16 bf16x8 __attribute__((ext_vector_type(8)));
typedef float floatx4 __attribute__((ext_vector_type(4)));

#define BB 2
#define NN 2048
#define DD 512
#define HH 8
#define HD 64
#define RR 64
#define D3 1536
#define NEG_BIG (-1e30f)
#define TQ 32
#define TBAND 160

// async global->LDS, 16B per lane; LDS dest must be wave-uniform base + lane*16
#define GL2LDS16(g, l)                                                        \
    __builtin_amdgcn_global_load_lds(                                         \
        (const __attribute__((address_space(1))) void*)(const void*)(g),      \
        (__attribute__((address_space(3))) void*)(void*)(l), 16, 0, 0)

// ---------------------------------------- f32 -> bf16 convert+TRANSPOSE (all)
// One kernel for all four weights.  W [K][N] f32 -> Wt [N][K] bf16.
__global__ __launch_bounds__(256) void cvt_all_kernel(
    const float* __restrict__ qkv_w, const float* __restrict__ proj_w,
    const float* __restrict__ m1w, const float* __restrict__ m2w,
    bf16* __restrict__ wqt, bf16* __restrict__ wpt,
    bf16* __restrict__ w1t, bf16* __restrict__ w2t) {
    __shared__ bf16 Ts[64][72];
    const int tid = threadIdx.x;
    int bid = blockIdx.x;
    const float* W; bf16* Wt; int K, N, bx, by;
    if (bid < 192)      { W = qkv_w;  Wt = wqt; K = 512;  N = 1536; bx = bid % 24; by = bid / 24; }
    else if (bid < 256) { bid -= 192; W = proj_w; Wt = wpt; K = 512;  N = 512;  bx = bid % 8;  by = bid / 8; }
    else if (bid < 384) { bid -= 256; W = m1w;  Wt = w1t; K = 512;  N = 1024; bx = bid % 16; by = bid / 16; }
    else                { bid -= 384; W = m2w;  Wt = w2t; K = 1024; N = 512;  bx = bid % 8;  by = bid / 8; }
    const int n0 = bx * 64, k0 = by * 64;
    #pragma unroll
    for (int i = 0; i < 4; i++) {
        int r = (tid >> 4) + i * 16;
        int c = (tid & 15) * 4;
        floatx4 v = *(const floatx4*)(W + (size_t)(k0 + r) * N + n0 + c);
        #pragma unroll
        for (int e = 0; e < 4; e++) Ts[r][c + e] = (bf16)v[e];
    }
    __syncthreads();
    #pragma unroll
    for (int i = 0; i < 4; i++) {
        int n = (tid >> 4) + i * 16;
        int k = (tid & 15) * 4;
        bf16x4 o;
        #pragma unroll
        for (int e = 0; e < 4; e++) o[e] = Ts[k + e][n];
        *(bf16x4*)(Wt + (size_t)(n0 + n) * K + k0 + k) = o;
    }
}

// ---------------------------------------------------------------- block reduce
__device__ inline float block_reduce_sum256(float v, float* sbuf) {
    const int tid = threadIdx.x;
    #pragma unroll
    for (int o = 32; o > 0; o >>= 1) v += __shfl_xor(v, o, 64);
    __syncthreads();
    if ((tid & 63) == 0) sbuf[tid >> 6] = v;
    __syncthreads();
    return sbuf[0] + sbuf[1] + sbuf[2] + sbuf[3];
}

// ---------------------------------------------------------------- LayerNorm
template <bool WANT_INV>
__global__ __launch_bounds__(256) void ln_kernel(
    const float* __restrict__ in, const float* __restrict__ gw,
    const float* __restrict__ bw, bf16* __restrict__ out,
    float* __restrict__ invnorm) {
    __shared__ float sbuf[4];
    const int row = blockIdx.x, tid = threadIdx.x;
    const int i0 = tid * 2;
    const float* ip = in + (size_t)row * DD;
    float v0 = ip[i0], v1 = ip[i0 + 1];
    float mean = block_reduce_sum256(v0 + v1, sbuf) * (1.f / DD);
    float d0 = v0 - mean, d1 = v1 - mean;
    float var = block_reduce_sum256(d0 * d0 + d1 * d1, sbuf) * (1.f / DD);
    float rs = rsqrtf(var + 1e-5f);
    float x0 = d0 * rs * gw[i0] + bw[i0];
    float x1 = d1 * rs * gw[i0 + 1] + bw[i0 + 1];
    out[(size_t)row * DD + i0] = (bf16)x0;
    out[(size_t)row * DD + i0 + 1] = (bf16)x1;
    if (WANT_INV) {
        float s2 = block_reduce_sum256(x0 * x0 + x1 * x1, sbuf);
        if (tid == 0) invnorm[row] = 1.f / fmaxf(sqrtf(s2), 1e-12f);
    }
}

// --------------------------------------------------- GEMM (MFMA, B^T input)
// Unchanged from R9: 64x64 tile, BK=64, dbuf LDS, granule XOR swizzle.
template <int MODE>
__global__ __launch_bounds__(256) void gemm_bt(
    const bf16* __restrict__ A, const bf16* __restrict__ Bt,
    const float* __restrict__ bias, const float* __restrict__ resid,
    void* __restrict__ out, int M, int N, int K) {
    __shared__ __align__(16) bf16 As[2][64 * 64];
    __shared__ __align__(16) bf16 Bs[2][64 * 64];
    const int tid = threadIdx.x;
    const int w = tid >> 6, lane = tid & 63;
    const int lr = lane & 15, lq = lane >> 4;
    const int rowBase = blockIdx.y * 64, colBase = blockIdx.x * 64;
    const int wm = (w >> 1) * 32, wn = (w & 1) * 32;

    floatx4 acc[2][2];
    #pragma unroll
    for (int i = 0; i < 2; i++)
        #pragma unroll
        for (int j = 0; j < 2; j++) acc[i][j] = (floatx4){0.f, 0.f, 0.f, 0.f};

    auto stage = [&](int buf, int k0) {
        #pragma unroll
        for (int i = 0; i < 2; i++) {
            int g = i * 256 + tid;
            int row = g >> 3, k8 = (g & 7) ^ (row & 7);
            GL2LDS16(A + (size_t)(rowBase + row) * K + k0 + k8 * 8, &As[buf][g * 8]);
        }
        #pragma unroll
        for (int i = 0; i < 2; i++) {
            int g = i * 256 + tid;
            int row = g >> 3, k8 = (g & 7) ^ (row & 7);
            GL2LDS16(Bt + (size_t)(colBase + row) * K + k0 + k8 * 8, &Bs[buf][g * 8]);
        }
    };

    const int nsteps = K >> 6;
    stage(0, 0);
    for (int s = 0; s < nsteps; s++) {
        __syncthreads();
        if (s + 1 < nsteps) stage((s + 1) & 1, (s + 1) * 64);
        const int buf = s & 1;
        #pragma unroll
        for (int kb = 0; kb < 2; kb++) {
            bf16x8 af[2], bfr[2];
            #pragma unroll
            for (int i = 0; i < 2; i++) {
                int row = wm + i * 16 + lr;
                int g = row * 8 + ((kb * 4 + lq) ^ (row & 7));
                af[i] = *(bf16x8*)&As[buf][g * 8];
            }
            #pragma unroll
            for (int j = 0; j < 2; j++) {
                int row = wn + j * 16 + lr;
                int g = row * 8 + ((kb * 4 + lq) ^ (row & 7));
                bfr[j] = *(bf16x8*)&Bs[buf][g * 8];
            }
            #pragma unroll
            for (int i = 0; i < 2; i++)
                #pragma unroll
                for (int j = 0; j < 2; j++)
                    acc[i][j] = __builtin_amdgcn_mfma_f32_16x16x32_bf16(
                        af[i], bfr[j], acc[i][j], 0, 0, 0);
        }
    }

    #pragma unroll
    for (int i = 0; i < 2; i++) {
        #pragma unroll
        for (int j = 0; j < 2; j++) {
            #pragma unroll
            for (int r = 0; r < 4; r++) {
                int row = rowBase + wm + i * 16 + lq * 4 + r;
                int col = colBase + wn + j * 16 + lr;
                size_t idx = (size_t)row * N + col;
                float v = acc[i][j][r] + bias[col];
                if (MODE == 0) {
                    ((bf16*)out)[idx] = (bf16)v;
                } else if (MODE == 1) {
                    ((float*)out)[idx] = v + resid[idx];
                } else if (MODE == 2) {
                    float g = 0.5f * v * (1.f + erff(v * 0.70710678118654752f));
                    ((bf16*)out)[idx] = (bf16)g;
                } else {
                    ((float*)out)[idx] = v + resid[idx];
                }
            }
        }
    }
}

// ------------------------------------------------------------- corr kernel
// One block per (b, n0): corr[q][j] = x̂(n0+q)·x̂(n0-64+j), pre-scaled, f32 out.
__global__ __launch_bounds__(256) void corr_kernel(
    const bf16* __restrict__ x, const float* __restrict__ invnorm,
    float* __restrict__ corr_g) {
    __shared__ __align__(16) bf16 Xc[TBAND * 72];   // 72 = 64 data + 8 pad
    __shared__ float invb[TBAND];
    const int tid = threadIdx.x;
    const int b = blockIdx.x & 1, n0 = (blockIdx.x >> 1) * TQ;
    const int bN = b * NN;
    const int w = tid >> 6, lane = tid & 63;
    const int lr = lane & 15, lq = lane >> 4;
    const int rowHalf = (w >> 1) * 16, colBase = (w & 1) * 80;

    if (tid < TBAND) {
        int mc = min(max(n0 - RR + tid, 0), NN - 1);
        invb[tid] = invnorm[bN + mc];
    }

    floatx4 cacc[5];
    #pragma unroll
    for (int t = 0; t < 5; t++) cacc[t] = (floatx4){0.f, 0.f, 0.f, 0.f};

    for (int c = 0; c < 8; c++) {
        __syncthreads();
        #pragma unroll
        for (int rr = 0; rr < 6; rr++) {
            int G = rr * 256 + tid;
            if (G < 1440) {                       // 160 rows x 9 granules
                int j = G / 9, gc = G % 9;
                int gcs = min(gc, 7);
                int mc = min(max(n0 - RR + j, 0), NN - 1);
                GL2LDS16(x + (size_t)(bN + mc) * DD + c * 64 + gcs * 8, Xc + G * 8);
            }
        }
        __syncthreads();
        #pragma unroll
        for (int kb = 0; kb < 2; kb++) {
            bf16x8 a = *(bf16x8*)&Xc[(64 + rowHalf + lr) * 72 + kb * 32 + lq * 8];
            #pragma unroll
            for (int t = 0; t < 5; t++) {
                bf16x8 bb = *(bf16x8*)&Xc[(colBase + t * 16 + lr) * 72 + kb * 32 + lq * 8];
                cacc[t] = __builtin_amdgcn_mfma_f32_16x16x32_bf16(a, bb, cacc[t], 0, 0, 0);
            }
        }
    }

    float invq[4];
    #pragma unroll
    for (int r = 0; r < 4; r++) invq[r] = invb[64 + rowHalf + lq * 4 + r];
    const size_t cbase = (size_t)blockIdx.x * TQ * TBAND;
    #pragma unroll
    for (int t = 0; t < 5; t++) {
        float invk = invb[colBase + t * 16 + lr];
        #pragma unroll
        for (int r = 0; r < 4; r++)
            corr_g[cbase + (size_t)(rowHalf + lq * 4 + r) * TBAND + colBase + t * 16 + lr] =
                cacc[t][r] * invq[r] * invk;
    }
}

// --------------------------------------------------------- V transpose kernel
// qkvb V-part [4096][h*64+d] -> vt_g[(h*64+d)][4096]
__global__ __launch_bounds__(256) void vtrans_kernel(
    const bf16* __restrict__ qkvb, bf16* __restrict__ vt_g) {
    __shared__ bf16 Ts[64][72];
    const int tid = threadIdx.x;
    const int r0 = blockIdx.x * 64;
    const int h = blockIdx.y;
    #pragma unroll
    for (int i = 0; i < 2; i++) {
        int r = (tid >> 3) + i * 32, c8 = tid & 7;
        *(bf16x8*)&Ts[r][c8 * 8] =
            *(const bf16x8*)(qkvb + (size_t)(r0 + r) * D3 + 2 * DD + h * HD + c8 * 8);
    }
    __syncthreads();
    #pragma unroll
    for (int i = 0; i < 2; i++) {
        int d = (tid >> 3) + i * 32, c8 = (tid & 7) * 8;
        bf16x8 o;
        #pragma unroll
        for (int e = 0; e < 8; e++) o[e] = Ts[c8 + e][d];
        *(bf16x8*)(vt_g + (((size_t)(h * HD + d)) << 12) + r0 + c8) = o;
    }
}

// ---------------------------------------------------------------- attention
// Block: TQ=32 queries, band 160, 4 of 8 heads.  corr precomputed; V^T global.
// All staging via global_load_lds; padded strides -> fragment reads ~2-way.
__global__ __launch_bounds__(256) void attn_kernel(
    const bf16* __restrict__ qkv, const bf16* __restrict__ vt_g,
    const float* __restrict__ corr_g, const float* __restrict__ rep_scale,
    const float* __restrict__ rel_bias, bf16* __restrict__ upd) {
    __shared__ __align__(16) bf16 Qs[TQ * 264];     // 256 data + 8 pad
    __shared__ __align__(16) bf16 Ks[TBAND * 72];   // 64 data + 8 pad
    __shared__ __align__(16) bf16 Vt[64 * 168];     // 160 data + 8 pad
    __shared__ __align__(16) bf16 Ps[TQ * 168];
    __shared__ float relb[4][192];
    __shared__ float rmax2[TQ][2];
    __shared__ float rsum2[TQ][2];

    const int tid = threadIdx.x;
    const int bid = blockIdx.x;
    const int b = bid & 1;
    const int h0 = ((bid >> 1) & 1) * 4;
    const int n0 = (bid >> 2) * TQ;
    const int bN = b * NN;
    const int w = tid >> 6, lane = tid & 63;
    const int lr = lane & 15, lq = lane >> 4;
    const int rowHalf = (w >> 1) * 16;
    const int colBase = (w & 1) * 80;
    const int c2 = (w & 1) * 32;

    for (int idx = tid; idx < 4 * 191; idx += 256) {
        int hh = idx / 191, dh = idx - hh * 191;
        relb[hh][dh] = rel_bias[(size_t)(dh + (NN - 1 - 95)) * HH + h0 + hh];
    }

    float corrv[5][4];
    {
        const size_t cbase = (size_t)(((bid >> 2) << 1) | b) * TQ * TBAND;
        #pragma unroll
        for (int t = 0; t < 5; t++)
            #pragma unroll
            for (int r = 0; r < 4; r++)
                corrv[t][r] = corr_g[cbase + (size_t)(rowHalf + lq * 4 + r) * TBAND +
                                     colBase + t * 16 + lr];
    }

    // stage Q for all 4 heads: 32 rows x 33 granules = 1056
    #pragma unroll
    for (int rr = 0; rr < 5; rr++) {
        int G = rr * 256 + tid;
        if (G < 1056) {
            int q = G / 33, gc = G % 33;
            int gcs = min(gc, 31);
            GL2LDS16(qkv + (size_t)(bN + n0 + q) * D3 + h0 * HD + gcs * 8, Qs + G * 8);
        }
    }

    for (int h = h0; h < h0 + 4; h++) {
        __syncthreads();   // h0: drain Qs; later: protect Ks/Vt/Ps reuse
        #pragma unroll
        for (int rr = 0; rr < 6; rr++) {          // K: 160 x 9 granules = 1440
            int G = rr * 256 + tid;
            if (G < 1440) {
                int j = G / 9, gc = G % 9;
                int gcs = min(gc, 7);
                int mc = min(max(n0 - RR + j, 0), NN - 1);
                GL2LDS16(qkv + (size_t)(bN + mc) * D3 + DD + h * HD + gcs * 8, Ks + G * 8);
            }
        }
        #pragma unroll
        for (int rr = 0; rr < 6; rr++) {          // V^T: 64 x 21 granules = 1344
            int G = rr * 256 + tid;
            if (G < 1344) {
                int d = G / 21, gc = G % 21;
                int nsrc = min(max(n0 - RR + gc * 8, 0), NN - 8);
                GL2LDS16(vt_g + (((size_t)(h * HD + d)) << 12) + bN + nsrc, Vt + G * 8);
            }
        }
        __syncthreads();   // drain K/V

        floatx4 sacc[5];
        #pragma unroll
        for (int t = 0; t < 5; t++) sacc[t] = (floatx4){0.f, 0.f, 0.f, 0.f};
        #pragma unroll
        for (int kb = 0; kb < 2; kb++) {
            bf16x8 a = *(bf16x8*)&Qs[(rowHalf + lr) * 264 + (h - h0) * 64 + kb * 32 + lq * 8];
            #pragma unroll
            for (int t = 0; t < 5; t++) {
                bf16x8 bb = *(bf16x8*)&Ks[(colBase + t * 16 + lr) * 72 + kb * 32 + lq * 8];
                sacc[t] = __builtin_amdgcn_mfma_f32_16x16x32_bf16(a, bb, sacc[t], 0, 0, 0);
            }
        }

        const float srep = rep_scale[h];
        float l[5][4];
        float mx[4] = {NEG_BIG, NEG_BIG, NEG_BIG, NEG_BIG};
        #pragma unroll
        for (int t = 0; t < 5; t++) {
            int j = colBase + t * 16 + lr;
            int m = n0 - RR + j;
            #pragma unroll
            for (int r = 0; r < 4; r++) {
                int qi = rowHalf + lq * 4 + r;
                int relidx = qi + RR - j;
                bool valid = (relidx >= -RR) && (relidx <= RR) && (m >= 0) && (m < NN);
                float lv = sacc[t][r] * 0.125f + corrv[t][r] * srep +
                           relb[h - h0][relidx + 95];
                l[t][r] = valid ? lv : NEG_BIG;
                mx[r] = fmaxf(mx[r], l[t][r]);
            }
        }
        #pragma unroll
        for (int r = 0; r < 4; r++)
            #pragma unroll
            for (int mk = 1; mk <= 8; mk <<= 1)
                mx[r] = fmaxf(mx[r], __shfl_xor(mx[r], mk, 64));
        if (lr == 0) {
            #pragma unroll
            for (int r = 0; r < 4; r++) rmax2[rowHalf + lq * 4 + r][w & 1] = mx[r];
        }
        __syncthreads();

        float rm[4], sm[4];
        #pragma unroll
        for (int r = 0; r < 4; r++) {
            int row = rowHalf + lq * 4 + r;
            rm[r] = fmaxf(rmax2[row][0], rmax2[row][1]);
            sm[r] = 0.f;
        }
        #pragma unroll
        for (int t = 0; t < 5; t++) {
            int j = colBase + t * 16 + lr;
            #pragma unroll
            for (int r = 0; r < 4; r++) {
                float pv = __expf(l[t][r] - rm[r]);
                sm[r] += pv;
                Ps[(rowHalf + lq * 4 + r) * 168 + j] = (bf16)pv;
            }
        }
        #pragma unroll
        for (int r = 0; r < 4; r++)
            #pragma unroll
            for (int mk = 1; mk <= 8; mk <<= 1)
                sm[r] += __shfl_xor(sm[r], mk, 64);
        if (lr == 0) {
            #pragma unroll
            for (int r = 0; r < 4; r++) rsum2[rowHalf + lq * 4 + r][w & 1] = sm[r];
        }
        __syncthreads();

        floatx4 oacc[2] = {(floatx4){0.f, 0.f, 0.f, 0.f}, (floatx4){0.f, 0.f, 0.f, 0.f}};
        #pragma unroll
        for (int kb = 0; kb < 5; kb++) {
            bf16x8 a = *(bf16x8*)&Ps[(rowHalf + lr) * 168 + kb * 32 + lq * 8];
            #pragma unroll
            for (int tt = 0; tt < 2; tt++) {
                bf16x8 bb = *(bf16x8*)&Vt[(c2 + tt * 16 + lr) * 168 + kb * 32 + lq * 8];
                oacc[tt] = __builtin_amdgcn_mfma_f32_16x16x32_bf16(a, bb, oacc[tt], 0, 0, 0);
            }
        }
        #pragma unroll
        for (int r = 0; r < 4; r++) {
            int row = rowHalf + lq * 4 + r;
            float rinv = 1.f / (rsum2[row][0] + rsum2[row][1]);
            #pragma unroll
            for (int tt = 0; tt < 2; tt++) {
                upd[(size_t)(bN + n0 + row) * DD + h * HD + c2 + tt * 16 + lr] =
                    (bf16)(oacc[tt][r] * rinv);
            }
        }
    }
}

// ---------------------------------------------------------------- launch
// Inputs FLOAT32; OUTPUT FLOAT32.
extern "C" void kernel_launch(void* const* d_in, const int* in_sizes, int n_in,
                              void* d_out, int out_size, void* d_ws,
                              size_t ws_size, hipStream_t stream) {
    const float* nodes  = (const float*)d_in[0];
    const float* ln1_g  = (const float*)d_in[1];
    const float* ln1_b  = (const float*)d_in[2];
    const float* qkv_w  = (const float*)d_in[3];
    const float* qkv_b  = (const float*)d_in[4];
    const float* proj_w = (const float*)d_in[5];
    const float* proj_b = (const float*)d_in[6];
    const float* rep_s  = (const float*)d_in[7];
    const float* rel_b  = (const float*)d_in[8];
    const float* ln2_g  = (const float*)d_in[9];
    const float* ln2_b  = (const float*)d_in[10];
    const float* mlp_w1 = (const float*)d_in[11];
    const float* mlp_b1 = (const float*)d_in[12];
    const float* mlp_w2 = (const float*)d_in[13];
    const float* mlp_b2 = (const float*)d_in[14];

    char* p = (char*)d_ws;
    float* invn = (float*)p;            p += (size_t)1 << 20;
    bf16*  wqt  = (bf16*)p;             p += (size_t)DD * D3 * 2;
    bf16*  wpt  = (bf16*)p;             p += (size_t)DD * DD * 2;
    bf16*  w1t  = (bf16*)p;             p += (size_t)DD * 2 * DD * 2;
    bf16*  w2t  = (bf16*)p;             p += (size_t)2 * DD * DD * 2;
    bf16*  x    = (bf16*)p;             p += (size_t)BB * NN * DD * 2;
    bf16*  qkvb = (bf16*)p;             p += (size_t)BB * NN * D3 * 2;
    char*  regA = p;                    p += (size_t)BB * NN * DD * 4;   // 8 MiB
    // region A overlays: corr_g (2.62M) + vt_g (4M) live before gemm<1>;
    // mid (8M f32) written by gemm<1> after attn consumed them.
    float* corr_g = (float*)regA;
    bf16*  vt_g   = (bf16*)(regA + (size_t)BB * (NN / TQ) * TQ * TBAND * 4);
    float* mid    = (float*)regA;
    bf16*  y    = x;                // alias: x dead after corr/gemm<0>
    bf16*  hgl  = qkvb;             // alias: qkvb dead after attn_kernel
    bf16*  upd  = (bf16*)d_out;     // scratch; consumed by gemm<1>, then
                                    // d_out fully rewritten (f32) by gemm<3>

    const int M = BB * NN;  // 4096

    cvt_all_kernel<<<512, 256, 0, stream>>>(qkv_w, proj_w, mlp_w1, mlp_w2,
                                            wqt, wpt, w1t, w2t);
    ln_kernel<true><<<M, 256, 0, stream>>>(nodes, ln1_g, ln1_b, x, invn);
    corr_kernel<<<BB * (NN / TQ), 256, 0, stream>>>(x, invn, corr_g);
    gemm_bt<0><<<dim3(D3 / 64, M / 64), 256, 0, stream>>>(
        x, wqt, qkv_b, nullptr, qkvb, M, D3, DD);
    vtrans_kernel<<<dim3(M / 64, HH), 256, 0, stream>>>(qkvb, vt_g);
    attn_kernel<<<(NN / TQ) * 2 * BB, 256, 0, stream>>>(
        qkvb, vt_g, corr_g, rep_s, rel_b, upd);
    gemm_bt<1><<<dim3(DD / 64, M / 64), 256, 0, stream>>>(
        upd, wpt, proj_b, nodes, mid, M, DD, DD);
    ln_kernel<false><<<M, 256, 0, stream>>>(mid, ln2_g, ln2_b, y, nullptr);
    gemm_bt<2><<<dim3(2 * DD / 64, M / 64), 256, 0, stream>>>(
        y, w1t, mlp_b1, nullptr, hgl, M, 2 * DD, DD);
    gemm_bt<3><<<dim3(DD / 64, M / 64), 256, 0, stream>>>(
        hgl, w2t, mlp_b2, mid, (float*)d_out, M, DD, 2 * DD);
}